// Round 6
// baseline (343.108 us; speedup 1.0000x reference)
//
#include <hip/hip_runtime.h>

#define NN 50000
#define NE 1600000
#define NT (NE + NN)   // total edges incl self loops
#define NF 512
#define F1 128
#define NH 8
#define F2 40

#define NB 196         // dst buckets of 256 nodes
#define BCAP 10240     // per-bucket staging capacity (mean 8163, sd ~90)
#define TILE 4096

typedef __attribute__((ext_vector_type(8))) short short8;
typedef __attribute__((ext_vector_type(4))) short short4v;
typedef __attribute__((ext_vector_type(4))) float f32x4;

__device__ __forceinline__ float lrelu(float x) { return fmaxf(x, 0.2f * x); }

__device__ __forceinline__ unsigned short f2bf(float f) {
  unsigned int u = __float_as_uint(f);
  u += 0x7fffu + ((u >> 16) & 1u);  // RNE
  return (unsigned short)(u >> 16);
}
__device__ __forceinline__ float bfhi(unsigned int dw) { return __uint_as_float(dw & 0xffff0000u); }
__device__ __forceinline__ float bflo(unsigned int dw) { return __uint_as_float(dw << 16); }
__device__ __forceinline__ float elu(float x) { return x > 0.f ? x : __expf(x) - 1.f; }

// ---------------- CSR build phase A: bucket-bin edges with LDS tile sort ----------------
__global__ __launch_bounds__(256) void k_binA(const int* __restrict__ esrc,
                                              const int* __restrict__ edst,
                                              const float* __restrict__ ew,
                                              int* __restrict__ bktCnt,
                                              uint2* __restrict__ bSrcEw,
                                              unsigned short* __restrict__ bDst) {
  __shared__ int cnt[NB];
  __shared__ int scn[NB];
  __shared__ int gbase[NB];
  __shared__ int cur[NB];
  __shared__ int tmp[256];
  __shared__ uint2 stSE[TILE];
  __shared__ unsigned short stD[TILE];
  const int t = threadIdx.x;
  const int e0 = blockIdx.x * TILE;

  for (int b = t; b < NB; b += 256) cnt[b] = 0;
  __syncthreads();

  unsigned int sd[16];
  float wv[16];
#pragma unroll
  for (int u = 0; u < 16; ++u) {
    int e = e0 + t + 256 * u;
    if (e < NE) {
      unsigned int s = (unsigned int)esrc[e];
      unsigned int d = (unsigned int)edst[e];
      sd[u] = s | (d << 16);
      wv[u] = ew[e];
      atomicAdd(&cnt[d >> 8], 1);
    } else {
      sd[u] = 0xFFFFFFFFu;
    }
  }
  __syncthreads();

  // exclusive scan of cnt[0..NB) + global append reservation
  int v = (t < NB) ? cnt[t] : 0;
  tmp[t] = v;
  __syncthreads();
  for (int off = 1; off < 256; off <<= 1) {
    int a = (t >= off) ? tmp[t - off] : 0;
    __syncthreads();
    tmp[t] += a;
    __syncthreads();
  }
  if (t < NB) {
    scn[t] = tmp[t] - v;
    cur[t] = tmp[t] - v;
    gbase[t] = atomicAdd(&bktCnt[t], v);
  }
  __syncthreads();

  // bucket-sort tile into LDS
#pragma unroll
  for (int u = 0; u < 16; ++u) {
    if (sd[u] != 0xFFFFFFFFu) {
      unsigned int d = sd[u] >> 16;
      int p = atomicAdd(&cur[d >> 8], 1);
      stSE[p] = make_uint2(sd[u] & 0xFFFFu, __float_as_uint(wv[u]));
      stD[p] = (unsigned short)d;
    }
  }
  __syncthreads();

  // flush: contiguous runs per bucket -> coalesced global writes
  int tot = NE - e0;
  if (tot > TILE) tot = TILE;
  for (int k = t; k < tot; k += 256) {
    int d = stD[k];
    int b = d >> 8;
    int idx = gbase[b] + (k - scn[b]);
    bSrcEw[(size_t)b * BCAP + idx] = stSE[k];
    bDst[(size_t)b * BCAP + idx] = (unsigned short)d;
  }
}

// ---------------- CSR build: scan bucket totals (incl self loops) ----------------
__global__ void k_bscan(const int* __restrict__ bktCnt, int* __restrict__ base,
                        int* __restrict__ rs) {
  __shared__ int tmp[256];
  int t = threadIdx.x;
  int nInB = 0;
  if (t < NB) nInB = (t == NB - 1) ? (NN - (NB - 1) * 256) : 256;
  int v = (t < NB) ? bktCnt[t] + nInB : 0;
  tmp[t] = v;
  __syncthreads();
  for (int off = 1; off < 256; off <<= 1) {
    int a = (t >= off) ? tmp[t - off] : 0;
    __syncthreads();
    tmp[t] += a;
    __syncthreads();
  }
  if (t < NB) base[t] = tmp[t] - v;
  if (t == 0) rs[NN] = NT;
}

// ---------------- CSR build phase B: per-bucket local hist/scan/scatter ----------------
__global__ __launch_bounds__(256) void k_fillB(const int* __restrict__ bktCnt,
                                               const int* __restrict__ base,
                                               const uint2* __restrict__ bSrcEw,
                                               const unsigned short* __restrict__ bDst,
                                               const float* __restrict__ ew,
                                               int* __restrict__ rs,
                                               uint2* __restrict__ edge) {
  __shared__ int cnt[256], cur[256], tmp[256];
  const int b = blockIdx.x, t = threadIdx.x;
  const int n0 = b * 256;
  const int nNodes = (n0 + 256 <= NN) ? 256 : (NN - n0);
  const int cE = bktCnt[b];
  const int gb = base[b];

  cnt[t] = 0;
  __syncthreads();
  for (int k = t; k < cE; k += 256) atomicAdd(&cnt[bDst[(size_t)b * BCAP + k] & 255], 1);
  __syncthreads();

  int v = (t < nNodes) ? cnt[t] + 1 : 0;  // +1 self loop
  tmp[t] = v;
  __syncthreads();
  for (int off = 1; off < 256; off <<= 1) {
    int a = (t >= off) ? tmp[t - off] : 0;
    __syncthreads();
    tmp[t] += a;
    __syncthreads();
  }
  int off_ = tmp[t] - v;  // exclusive
  if (t < nNodes) {
    rs[n0 + t] = gb + off_;
    cur[t] = off_ + 1;  // slot 0 = self loop
    edge[(size_t)gb + off_] = make_uint2((unsigned int)(n0 + t), __float_as_uint(ew[NE + n0 + t]));
  }
  __syncthreads();

  for (int k = t; k < cE; k += 256) {
    uint2 se = bSrcEw[(size_t)b * BCAP + k];
    int d = bDst[(size_t)b * BCAP + k] & 255;
    int p = atomicAdd(&cur[d], 1);
    edge[(size_t)gb + p] = se;  // window owned by this block -> XCD-local lines
  }
}

// -------- GEMM1 (MFMA bf16): h1b_hm[head][N][16] = bf16(x @ W1^T), head-major --------
__global__ __launch_bounds__(256) void k_gemm1(const float* __restrict__ x,
                                               const float* __restrict__ W1,
                                               unsigned short* __restrict__ h1b_hm) {
  __shared__ unsigned short As[128 * 40];  // 128 rows x 32 k, pad to 40
  __shared__ unsigned short Bs[128 * 40];  // 128 cols x 32 k
  const int t = threadIdx.x;
  const int w = t >> 6, lane = t & 63;
  const int g16 = lane >> 4, r16 = lane & 15;
  const int m0 = blockIdx.x * 128;

  f32x4 acc[2][8];
#pragma unroll
  for (int a = 0; a < 2; ++a)
#pragma unroll
    for (int b = 0; b < 8; ++b) acc[a][b] = (f32x4){0.f, 0.f, 0.f, 0.f};

  for (int kc = 0; kc < NF; kc += 32) {
    __syncthreads();
#pragma unroll
    for (int i = 0; i < 4; ++i) {
      int idx = t + 256 * i;         // 0..1023
      int row = idx >> 3;            // 0..127
      int k4 = (idx & 7) << 2;       // 0..28
      int n = m0 + row;
      float4 v = make_float4(0.f, 0.f, 0.f, 0.f);
      if (n < NN) v = *(const float4*)&x[(size_t)n * NF + kc + k4];
      short4v b;
      b[0] = (short)f2bf(v.x); b[1] = (short)f2bf(v.y);
      b[2] = (short)f2bf(v.z); b[3] = (short)f2bf(v.w);
      *(short4v*)&As[row * 40 + k4] = b;
    }
#pragma unroll
    for (int i = 0; i < 4; ++i) {
      int idx = t + 256 * i;
      int col = idx >> 3;
      int k4 = (idx & 7) << 2;
      float4 v = *(const float4*)&W1[(size_t)col * NF + kc + k4];
      short4v b;
      b[0] = (short)f2bf(v.x); b[1] = (short)f2bf(v.y);
      b[2] = (short)f2bf(v.z); b[3] = (short)f2bf(v.w);
      *(short4v*)&Bs[col * 40 + k4] = b;
    }
    __syncthreads();

    short8 afr[2], bfr[8];
#pragma unroll
    for (int mi = 0; mi < 2; ++mi)
      afr[mi] = *(const short8*)&As[(w * 32 + mi * 16 + r16) * 40 + g16 * 8];
#pragma unroll
    for (int nj = 0; nj < 8; ++nj)
      bfr[nj] = *(const short8*)&Bs[(nj * 16 + r16) * 40 + g16 * 8];
#pragma unroll
    for (int mi = 0; mi < 2; ++mi)
#pragma unroll
      for (int nj = 0; nj < 8; ++nj)
        acc[mi][nj] = __builtin_amdgcn_mfma_f32_16x16x32_bf16(afr[mi], bfr[nj], acc[mi][nj], 0, 0, 0);
  }

  // col block nj == head nj (features 16nj..16nj+15); head-major store
#pragma unroll
  for (int mi = 0; mi < 2; ++mi)
#pragma unroll
    for (int r = 0; r < 4; ++r) {
      int grow = m0 + w * 32 + mi * 16 + g16 * 4 + r;
      if (grow < NN) {
#pragma unroll
        for (int nj = 0; nj < 8; ++nj)
          h1b_hm[((size_t)nj * NN + grow) * 16 + r16] = f2bf(acc[mi][nj][r]);
      }
    }
}

// ------- per-node attention halves, layer 1 (head-major): al/ar [head][N] -------
__global__ void k_alr1(const unsigned int* __restrict__ h1b_hm32, const float* __restrict__ attl,
                       const float* __restrict__ attr, float* __restrict__ al_hm,
                       float* __restrict__ ar_hm) {
  int n = blockIdx.x * 256 + threadIdx.x;
  int h = blockIdx.y;
  if (n >= NN) return;
  const unsigned int* row = h1b_hm32 + ((size_t)h * NN + n) * 8;
  float a = 0.f, b = 0.f;
#pragma unroll
  for (int c = 0; c < 8; ++c) {
    unsigned int hv = row[c];
    float v0 = bflo(hv), v1 = bfhi(hv);
    a = fmaf(v0, attl[h * 16 + 2 * c], a);
    a = fmaf(v1, attl[h * 16 + 2 * c + 1], a);
    b = fmaf(v0, attr[h * 16 + 2 * c], b);
    b = fmaf(v1, attr[h * 16 + 2 * c + 1], b);
  }
  al_hm[(size_t)h * NN + n] = a;
  ar_hm[(size_t)h * NN + n] = b;
}

// ---- layer-1 aggregation, head-sliced: block = 8 nodes x 1 head (blockIdx&7 -> XCD) ----
// wave = 2 nodes x 4 edge-slots x 8 feature-dwords; slab per head is L2-resident
__global__ __launch_bounds__(256) void k_agg1h(const int* __restrict__ rs,
                                               const uint2* __restrict__ edge,
                                               const unsigned int* __restrict__ h1b_hm32,
                                               const float* __restrict__ al_hm,
                                               const float* __restrict__ ar_hm,
                                               const float* __restrict__ b1,
                                               unsigned int* __restrict__ h1e_hm) {
  const int t = threadIdx.x;
  const int lane = t & 63;
  const int wid = t >> 6;
  const int h = blockIdx.x & 7;
  const int f = lane & 7;
  const int s = (lane >> 3) & 3;
  const int i = (blockIdx.x >> 3) * 8 + wid * 2 + (lane >> 5);
  if (i >= NN) return;
  const int base = rs[i], end = rs[i + 1];
  const unsigned int* tab = h1b_hm32 + (size_t)h * NN * 8;
  const float* alh = al_hm + (size_t)h * NN;
  const float arh = ar_hm[(size_t)h * NN + i];
  float sa = 0.f, sb = 0.f, a0 = 0.f, a1 = 0.f, c0 = 0.f, c1 = 0.f;

  int e = base + s;
  for (; e + 4 < end; e += 8) {
    uint2 ceA = edge[e];
    uint2 ceB = edge[e + 4];
    int jA = (int)ceA.x, jB = (int)ceB.x;
    float lA = alh[jA], lB = alh[jB];
    unsigned int hA = tab[(size_t)jA * 8 + f];
    unsigned int hB = tab[(size_t)jB * 8 + f];
    float qA = __expf(lrelu(lA + arh));
    float qB = __expf(lrelu(lB + arh));
    float pA = qA * __uint_as_float(ceA.y);
    float pB = qB * __uint_as_float(ceB.y);
    sa += qA;
    sb += qB;
    a0 = fmaf(pA, bflo(hA), a0);
    a1 = fmaf(pA, bfhi(hA), a1);
    c0 = fmaf(pB, bflo(hB), c0);
    c1 = fmaf(pB, bfhi(hB), c1);
  }
  if (e < end) {
    uint2 ce = edge[e];
    int j = (int)ce.x;
    unsigned int hv = tab[(size_t)j * 8 + f];
    float q = __expf(lrelu(alh[j] + arh));
    float p = q * __uint_as_float(ce.y);
    sa += q;
    a0 = fmaf(p, bflo(hv), a0);
    a1 = fmaf(p, bfhi(hv), a1);
  }
  sa += sb;
  a0 += c0;
  a1 += c1;
#pragma unroll
  for (int off = 8; off <= 16; off <<= 1) {
    sa += __shfl_xor(sa, off);
    a0 += __shfl_xor(a0, off);
    a1 += __shfl_xor(a1, off);
  }
  if (s == 0) {
    float inv = 1.f / sa;
    float2 bb = ((const float2*)b1)[h * 8 + f];
    float o0 = elu(fmaf(a0, inv, bb.x));
    float o1 = elu(fmaf(a1, inv, bb.y));
    h1e_hm[((size_t)h * NN + i) * 8 + f] =
        (unsigned int)f2bf(o0) | ((unsigned int)f2bf(o1) << 16);
  }
}

// ---------------- GEMM2: hp2b[N][40] = bf16(h1e @ W2^T), 24 nodes/block ----------------
__global__ __launch_bounds__(256) void k_gemm2(const unsigned int* __restrict__ h1e_hm,
                                               const float* __restrict__ W2,
                                               unsigned short* __restrict__ hp2b) {
  __shared__ float wl[40 * 132];
  __shared__ float hs[24 * 132];
  int t = threadIdx.x;
#pragma unroll
  for (int it = 0; it < 5; ++it) {
    int idx = t + 256 * it;  // 0..1279 float4s
    int c = idx >> 5, k4 = (idx & 31) << 2;
    *(float4*)&wl[c * 132 + k4] = *(const float4*)&W2[c * 128 + k4];
  }
  int n0 = blockIdx.x * 24;
#pragma unroll
  for (int it = 0; it < 6; ++it) {
    int idx = t + 256 * it;  // 0..1535
    int nl = idx >> 6, k = idx & 63;  // k: dword 0..63; head=k>>3, c=k&7
    int n = n0 + nl;
    unsigned int hv = (n < NN) ? h1e_hm[((size_t)(k >> 3) * NN + n) * 8 + (k & 7)] : 0u;
    hs[nl * 132 + 2 * k] = bflo(hv);
    hs[nl * 132 + 2 * k + 1] = bfhi(hv);
  }
  __syncthreads();
  for (int o = t; o < 960; o += 256) {
    int nl = o / 40, c = o - nl * 40;
    int n = n0 + nl;
    if (n < NN) {
      float a = 0.f;
#pragma unroll 8
      for (int k = 0; k < 128; k += 4) {
        float4 h = *(const float4*)&hs[nl * 132 + k];
        float4 w = *(const float4*)&wl[c * 132 + k];
        a = fmaf(h.x, w.x, a);
        a = fmaf(h.y, w.y, a);
        a = fmaf(h.z, w.z, a);
        a = fmaf(h.w, w.w, a);
      }
      hp2b[(size_t)n * 40 + c] = f2bf(a);
    }
  }
}

// ---------------- per-node attention halves, layer 2 ----------------
__global__ void k_alr2(const unsigned int* __restrict__ hp2b32, const float* __restrict__ attl,
                       const float* __restrict__ attr, float* __restrict__ al,
                       float* __restrict__ ar) {
  int n = blockIdx.x * 256 + threadIdx.x;
  if (n >= NN) return;
  const unsigned int* row = hp2b32 + (size_t)n * 20;  // 20 uints = 40 bf16
  float a = 0.f, b = 0.f;
#pragma unroll
  for (int c = 0; c < 20; ++c) {
    unsigned int hv = row[c];
    float v0 = bflo(hv), v1 = bfhi(hv);
    a = fmaf(v0, attl[2 * c], a);
    a = fmaf(v1, attl[2 * c + 1], a);
    b = fmaf(v0, attr[2 * c], b);
    b = fmaf(v1, attr[2 * c + 1], b);
  }
  al[n] = a;
  ar[n] = b;
}

// ---- layer-2 attention prepass: edge.y <- q*ew (in place), sinv[i] = 1/sum(q) ----
__global__ __launch_bounds__(256) void k_qw2(const int* __restrict__ rs,
                                             uint2* __restrict__ edge,
                                             const float* __restrict__ al2,
                                             const float* __restrict__ ar2,
                                             float* __restrict__ sinv) {
  const int lane = threadIdx.x & 63;
  const int i = blockIdx.x * 4 + (threadIdx.x >> 6);
  if (i >= NN) return;
  const int base = rs[i], end = rs[i + 1];
  const float ari = ar2[i];
  float s = 0.f;
  for (int e = base + lane; e < end; e += 64) {
    uint2 ce = edge[e];
    float q = __expf(lrelu(al2[(int)ce.x] + ari));
    s += q;
    ((float*)&edge[e])[1] = q * __uint_as_float(ce.y);
  }
#pragma unroll
  for (int off = 1; off < 64; off <<= 1) s += __shfl_xor(s, off);
  if (lane == 0) sinv[i] = 1.f / s;
}

// ---- layer-2 aggregation + bias + log_softmax: 1 node/wave, pre-weighted edges ----
// lane = s(edge slot, bit5) x f(feature dword 0..31, active f<20)
__global__ __launch_bounds__(256) void k_agg2(const int* __restrict__ rs,
                                              const uint2* __restrict__ edge,
                                              const unsigned int* __restrict__ hp2b32,
                                              const float* __restrict__ sinv,
                                              const float* __restrict__ b2,
                                              float* __restrict__ out) {
  const int lane = threadIdx.x & 63;
  const int i = blockIdx.x * 4 + (threadIdx.x >> 6);
  if (i >= NN) return;
  const int base = rs[i], end = rs[i + 1];
  const int s = lane >> 5;
  const int f = lane & 31;
  float a0 = 0.f, a1 = 0.f;

  int e = base + s;
  for (; e + 2 < end; e += 4) {
    uint2 ceA = edge[e];
    uint2 ceB = edge[e + 2];
    unsigned int hA = (f < 20) ? hp2b32[(size_t)ceA.x * 20 + f] : 0u;
    unsigned int hB = (f < 20) ? hp2b32[(size_t)ceB.x * 20 + f] : 0u;
    float pA = __uint_as_float(ceA.y), pB = __uint_as_float(ceB.y);
    a0 = fmaf(pA, bflo(hA), a0);
    a1 = fmaf(pA, bfhi(hA), a1);
    a0 = fmaf(pB, bflo(hB), a0);
    a1 = fmaf(pB, bfhi(hB), a1);
  }
  if (e < end) {
    uint2 ce = edge[e];
    unsigned int hv = (f < 20) ? hp2b32[(size_t)ce.x * 20 + f] : 0u;
    float p = __uint_as_float(ce.y);
    a0 = fmaf(p, bflo(hv), a0);
    a1 = fmaf(p, bfhi(hv), a1);
  }
  a0 += __shfl_xor(a0, 32);
  a1 += __shfl_xor(a1, 32);
  float inv = sinv[i];
  float v0 = -1e30f, v1 = -1e30f;
  if (f < 20) {
    v0 = fmaf(a0, inv, b2[2 * f]);
    v1 = fmaf(a1, inv, b2[2 * f + 1]);
  }
  float mx = fmaxf(v0, v1);
#pragma unroll
  for (int off = 1; off < 32; off <<= 1) mx = fmaxf(mx, __shfl_xor(mx, off, 32));
  float se = (f < 20) ? __expf(v0 - mx) + __expf(v1 - mx) : 0.f;
#pragma unroll
  for (int off = 1; off < 32; off <<= 1) se += __shfl_xor(se, off, 32);
  if (f < 20 && s == 0) {
    float ls = mx + __logf(se);
    ((float2*)(out + (size_t)i * 40))[f] = make_float2(v0 - ls, v1 - ls);
  }
}

extern "C" void kernel_launch(void* const* d_in, const int* in_sizes, int n_in,
                              void* d_out, int out_size, void* d_ws, size_t ws_size,
                              hipStream_t stream) {
  const float* x     = (const float*)d_in[0];
  const int*   esrc  = (const int*)d_in[1];
  const int*   edst  = (const int*)d_in[2];
  const float* ew    = (const float*)d_in[3];
  const float* W1    = (const float*)d_in[4];
  const float* attl1 = (const float*)d_in[5];
  const float* attr1 = (const float*)d_in[6];
  const float* b1    = (const float*)d_in[7];
  const float* W2    = (const float*)d_in[8];
  const float* attl2 = (const float*)d_in[9];
  const float* attr2 = (const float*)d_in[10];
  const float* b2    = (const float*)d_in[11];
  float* out = (float*)d_out;

  char* w = (char*)d_ws;
  auto take = [&](size_t bytes) {
    char* p = w;
    w += (bytes + 255) & ~(size_t)255;
    return p;
  };
  unsigned short* h1b  = (unsigned short*)take((size_t)NN * F1 * 2);  // head-major, 12.8 MB
  unsigned int*   h1eb = (unsigned int*)take((size_t)NN * 64 * 4);    // head-major, 12.8 MB
  float* al1 = (float*)take((size_t)NN * NH * 4);   // [head][N]
  float* ar1 = (float*)take((size_t)NN * NH * 4);   // [head][N]
  unsigned short* hp2b = (unsigned short*)take((size_t)NN * F2 * 2);
  float* al2 = (float*)take((size_t)NN * 4);
  float* ar2 = (float*)take((size_t)NN * 4);
  float* sinv = (float*)take((size_t)NN * 4);
  int*   rs  = (int*)take((size_t)(NN + 1) * 4);
  uint2* edge = (uint2*)take((size_t)NT * 8);
  int* bktCnt = (int*)take(NB * 4);
  int* bbase  = (int*)take(NB * 4);

  // staging arrays alias h1b/h1eb (CSR build fully precedes gemm1 on this stream)
  uint2* bSrcEw = (uint2*)h1b;                                          // 16.06 MB
  unsigned short* bDst = (unsigned short*)((char*)h1b + (size_t)NB * BCAP * 8);  // 4.01 MB

  // CSR build (by destination), self loop = slot 0 of each segment
  hipMemsetAsync(bktCnt, 0, NB * 4, stream);
  k_binA<<<(NE + TILE - 1) / TILE, 256, 0, stream>>>(esrc, edst, ew, bktCnt, bSrcEw, bDst);
  k_bscan<<<1, 256, 0, stream>>>(bktCnt, bbase, rs);
  k_fillB<<<NB, 256, 0, stream>>>(bktCnt, bbase, bSrcEw, bDst, ew, rs, edge);

  // layer 1
  k_gemm1<<<(NN + 127) / 128, 256, 0, stream>>>(x, W1, h1b);
  dim3 g1((NN + 255) / 256, NH);
  k_alr1<<<g1, 256, 0, stream>>>((const unsigned int*)h1b, attl1, attr1, al1, ar1);
  k_agg1h<<<(NN / 8) * 8, 256, 0, stream>>>(rs, edge, (const unsigned int*)h1b, al1, ar1, b1, h1eb);

  // layer 2
  k_gemm2<<<(NN + 23) / 24, 256, 0, stream>>>(h1eb, W2, hp2b);
  k_alr2<<<(NN + 255) / 256, 256, 0, stream>>>((const unsigned int*)hp2b, attl2, attr2, al2, ar2);
  k_qw2<<<(NN + 3) / 4, 256, 0, stream>>>(rs, edge, al2, ar2, sinv);
  k_agg2<<<(NN + 3) / 4, 256, 0, stream>>>(rs, edge, (const unsigned int*)hp2b, sinv, b2, out);
}

// Round 7
// 239.212 us; speedup vs baseline: 1.4343x; 1.4343x over previous
//
#include <hip/hip_runtime.h>

#define NN 50000
#define NE 1600000
#define NT (NE + NN)   // total edges incl self loops
#define NF 512
#define F1 128
#define NH 8
#define F2 40

#define NB 196         // dst buckets of 256 nodes
#define BCAP 10240     // per-bucket staging capacity (mean 8163, sd ~90)
#define TILE 4096

typedef __attribute__((ext_vector_type(8))) short short8;
typedef __attribute__((ext_vector_type(4))) short short4v;
typedef __attribute__((ext_vector_type(4))) float f32x4;
typedef __attribute__((ext_vector_type(2))) float f32x2;

__device__ __forceinline__ float lrelu(float x) { return fmaxf(x, 0.2f * x); }

__device__ __forceinline__ unsigned short f2bf(float f) {
  unsigned int u = __float_as_uint(f);
  u += 0x7fffu + ((u >> 16) & 1u);  // RNE
  return (unsigned short)(u >> 16);
}
__device__ __forceinline__ float bfhi(unsigned int dw) { return __uint_as_float(dw & 0xffff0000u); }
__device__ __forceinline__ float bflo(unsigned int dw) { return __uint_as_float(dw << 16); }
__device__ __forceinline__ float elu(float x) { return x > 0.f ? x : __expf(x) - 1.f; }

__device__ __forceinline__ unsigned char f2fp8(float v) {
  return (unsigned char)(__builtin_amdgcn_cvt_pk_fp8_f32(v, v, 0, false) & 0xFF);
}

// ---------------- CSR build phase A: bucket-bin edges with LDS tile sort ----------------
__global__ __launch_bounds__(256) void k_binA(const int* __restrict__ esrc,
                                              const int* __restrict__ edst,
                                              const float* __restrict__ ew,
                                              int* __restrict__ bktCnt,
                                              uint2* __restrict__ bSrcEw,
                                              unsigned short* __restrict__ bDst) {
  __shared__ int cnt[NB];
  __shared__ int scn[NB];
  __shared__ int gbase[NB];
  __shared__ int cur[NB];
  __shared__ int tmp[256];
  __shared__ uint2 stSE[TILE];
  __shared__ unsigned short stD[TILE];
  const int t = threadIdx.x;
  const int e0 = blockIdx.x * TILE;

  for (int b = t; b < NB; b += 256) cnt[b] = 0;
  __syncthreads();

  unsigned int sd[16];
  float wv[16];
#pragma unroll
  for (int u = 0; u < 16; ++u) {
    int e = e0 + t + 256 * u;
    if (e < NE) {
      unsigned int s = (unsigned int)esrc[e];
      unsigned int d = (unsigned int)edst[e];
      sd[u] = s | (d << 16);
      wv[u] = ew[e];
      atomicAdd(&cnt[d >> 8], 1);
    } else {
      sd[u] = 0xFFFFFFFFu;
    }
  }
  __syncthreads();

  int v = (t < NB) ? cnt[t] : 0;
  tmp[t] = v;
  __syncthreads();
  for (int off = 1; off < 256; off <<= 1) {
    int a = (t >= off) ? tmp[t - off] : 0;
    __syncthreads();
    tmp[t] += a;
    __syncthreads();
  }
  if (t < NB) {
    scn[t] = tmp[t] - v;
    cur[t] = tmp[t] - v;
    gbase[t] = atomicAdd(&bktCnt[t], v);
  }
  __syncthreads();

#pragma unroll
  for (int u = 0; u < 16; ++u) {
    if (sd[u] != 0xFFFFFFFFu) {
      unsigned int d = sd[u] >> 16;
      int p = atomicAdd(&cur[d >> 8], 1);
      stSE[p] = make_uint2(sd[u] & 0xFFFFu, __float_as_uint(wv[u]));
      stD[p] = (unsigned short)d;
    }
  }
  __syncthreads();

  int tot = NE - e0;
  if (tot > TILE) tot = TILE;
  for (int k = t; k < tot; k += 256) {
    int d = stD[k];
    int b = d >> 8;
    int idx = gbase[b] + (k - scn[b]);
    bSrcEw[(size_t)b * BCAP + idx] = stSE[k];
    bDst[(size_t)b * BCAP + idx] = (unsigned short)d;
  }
}

// ---------------- CSR build: scan bucket totals (incl self loops) ----------------
__global__ void k_bscan(const int* __restrict__ bktCnt, int* __restrict__ base,
                        int* __restrict__ rs) {
  __shared__ int tmp[256];
  int t = threadIdx.x;
  int nInB = 0;
  if (t < NB) nInB = (t == NB - 1) ? (NN - (NB - 1) * 256) : 256;
  int v = (t < NB) ? bktCnt[t] + nInB : 0;
  tmp[t] = v;
  __syncthreads();
  for (int off = 1; off < 256; off <<= 1) {
    int a = (t >= off) ? tmp[t - off] : 0;
    __syncthreads();
    tmp[t] += a;
    __syncthreads();
  }
  if (t < NB) base[t] = tmp[t] - v;
  if (t == 0) rs[NN] = NT;
}

// ---------------- CSR build phase B: per-bucket local hist/scan/scatter ----------------
__global__ __launch_bounds__(256) void k_fillB(const int* __restrict__ bktCnt,
                                               const int* __restrict__ base,
                                               const uint2* __restrict__ bSrcEw,
                                               const unsigned short* __restrict__ bDst,
                                               const float* __restrict__ ew,
                                               int* __restrict__ rs,
                                               uint2* __restrict__ edge) {
  __shared__ int cnt[256], cur[256], tmp[256];
  const int b = blockIdx.x, t = threadIdx.x;
  const int n0 = b * 256;
  const int nNodes = (n0 + 256 <= NN) ? 256 : (NN - n0);
  const int cE = bktCnt[b];
  const int gb = base[b];

  cnt[t] = 0;
  __syncthreads();
  for (int k = t; k < cE; k += 256) atomicAdd(&cnt[bDst[(size_t)b * BCAP + k] & 255], 1);
  __syncthreads();

  int v = (t < nNodes) ? cnt[t] + 1 : 0;  // +1 self loop
  tmp[t] = v;
  __syncthreads();
  for (int off = 1; off < 256; off <<= 1) {
    int a = (t >= off) ? tmp[t - off] : 0;
    __syncthreads();
    tmp[t] += a;
    __syncthreads();
  }
  int off_ = tmp[t] - v;  // exclusive
  if (t < nNodes) {
    rs[n0 + t] = gb + off_;
    cur[t] = off_ + 1;  // slot 0 = self loop
    edge[(size_t)gb + off_] = make_uint2((unsigned int)(n0 + t), __float_as_uint(ew[NE + n0 + t]));
  }
  __syncthreads();

  for (int k = t; k < cE; k += 256) {
    uint2 se = bSrcEw[(size_t)b * BCAP + k];
    int d = bDst[(size_t)b * BCAP + k] & 255;
    int p = atomicAdd(&cur[d], 1);
    edge[(size_t)gb + p] = se;
  }
}

// ---- GEMM1 (MFMA bf16): h1f[N][128] = fp8(x @ W1^T), packed via LDS repack ----
__global__ __launch_bounds__(256) void k_gemm1(const float* __restrict__ x,
                                               const float* __restrict__ W1,
                                               unsigned int* __restrict__ h1f32) {
  __shared__ unsigned short As[128 * 40];
  __shared__ unsigned short Bs[128 * 40];
  __shared__ unsigned int pk32[128 * 32];  // 16 KB fp8 repack buffer
  const int t = threadIdx.x;
  const int w = t >> 6, lane = t & 63;
  const int g16 = lane >> 4, r16 = lane & 15;
  const int m0 = blockIdx.x * 128;

  f32x4 acc[2][8];
#pragma unroll
  for (int a = 0; a < 2; ++a)
#pragma unroll
    for (int b = 0; b < 8; ++b) acc[a][b] = (f32x4){0.f, 0.f, 0.f, 0.f};

  for (int kc = 0; kc < NF; kc += 32) {
    __syncthreads();
#pragma unroll
    for (int i = 0; i < 4; ++i) {
      int idx = t + 256 * i;
      int row = idx >> 3;
      int k4 = (idx & 7) << 2;
      int n = m0 + row;
      float4 v = make_float4(0.f, 0.f, 0.f, 0.f);
      if (n < NN) v = *(const float4*)&x[(size_t)n * NF + kc + k4];
      short4v b;
      b[0] = (short)f2bf(v.x); b[1] = (short)f2bf(v.y);
      b[2] = (short)f2bf(v.z); b[3] = (short)f2bf(v.w);
      *(short4v*)&As[row * 40 + k4] = b;
    }
#pragma unroll
    for (int i = 0; i < 4; ++i) {
      int idx = t + 256 * i;
      int col = idx >> 3;
      int k4 = (idx & 7) << 2;
      float4 v = *(const float4*)&W1[(size_t)col * NF + kc + k4];
      short4v b;
      b[0] = (short)f2bf(v.x); b[1] = (short)f2bf(v.y);
      b[2] = (short)f2bf(v.z); b[3] = (short)f2bf(v.w);
      *(short4v*)&Bs[col * 40 + k4] = b;
    }
    __syncthreads();

    short8 afr[2], bfr[8];
#pragma unroll
    for (int mi = 0; mi < 2; ++mi)
      afr[mi] = *(const short8*)&As[(w * 32 + mi * 16 + r16) * 40 + g16 * 8];
#pragma unroll
    for (int nj = 0; nj < 8; ++nj)
      bfr[nj] = *(const short8*)&Bs[(nj * 16 + r16) * 40 + g16 * 8];
#pragma unroll
    for (int mi = 0; mi < 2; ++mi)
#pragma unroll
      for (int nj = 0; nj < 8; ++nj)
        acc[mi][nj] = __builtin_amdgcn_mfma_f32_16x16x32_bf16(afr[mi], bfr[nj], acc[mi][nj], 0, 0, 0);
  }

  // fp8-pack accumulators into LDS (byte per feature), then coalesced store
  unsigned char* pkb = (unsigned char*)pk32;
  __syncthreads();
#pragma unroll
  for (int mi = 0; mi < 2; ++mi)
#pragma unroll
    for (int r = 0; r < 4; ++r) {
      int row_l = w * 32 + mi * 16 + g16 * 4 + r;
#pragma unroll
      for (int nj = 0; nj < 8; ++nj)
        pkb[row_l * 128 + nj * 16 + r16] = f2fp8(acc[mi][nj][r]);
    }
  __syncthreads();
#pragma unroll
  for (int it = 0; it < 4; ++it) {
    int idx = t + 256 * it;  // 0..1023 uint4s
    int row = idx >> 3, q = idx & 7;
    int n = m0 + row;
    if (n < NN) ((uint4*)h1f32)[(size_t)n * 8 + q] = ((const uint4*)pk32)[row * 8 + q];
  }
}

// ------- per-node attention halves, layer 1: al/ar [N][8] (from fp8 table) -------
__global__ void k_alr1(const unsigned int* __restrict__ h1f32, const float* __restrict__ attl,
                       const float* __restrict__ attr, float* __restrict__ al,
                       float* __restrict__ ar) {
  int idx = blockIdx.x * 256 + threadIdx.x;
  if (idx >= NN * NH) return;
  int n = idx >> 3, h = idx & 7;
  const unsigned int* row = h1f32 + (size_t)n * 32 + h * 4;
  float a = 0.f, b = 0.f;
#pragma unroll
  for (int c = 0; c < 4; ++c) {
    unsigned int u = row[c];
    f32x2 lo = __builtin_amdgcn_cvt_pk_f32_fp8((int)u, false);
    f32x2 hi = __builtin_amdgcn_cvt_pk_f32_fp8((int)u, true);
    int f0 = h * 16 + 4 * c;
    a = fmaf(lo[0], attl[f0], a);
    a = fmaf(lo[1], attl[f0 + 1], a);
    a = fmaf(hi[0], attl[f0 + 2], a);
    a = fmaf(hi[1], attl[f0 + 3], a);
    b = fmaf(lo[0], attr[f0], b);
    b = fmaf(lo[1], attr[f0 + 1], b);
    b = fmaf(hi[0], attr[f0 + 2], b);
    b = fmaf(hi[1], attr[f0 + 3], b);
  }
  al[idx] = a;
  ar[idx] = b;
}

// ---- layer-1 aggregation: 2 nodes/wave (32-lane halves), plain exp, fp8 gather ----
// lane hl (0..31) owns features 4hl..4hl+3 (one uint = 4 fp8); head = hl>>2
__global__ __launch_bounds__(256) void k_agg1(const int* __restrict__ rs,
                                              const uint2* __restrict__ edge,
                                              const unsigned int* __restrict__ h1f32,
                                              const float* __restrict__ al,
                                              const float* __restrict__ ar,
                                              const float* __restrict__ b1,
                                              uint2* __restrict__ h1eb) {
  const int hl = threadIdx.x & 31;
  const int i = blockIdx.x * 8 + (threadIdx.x >> 5);
  if (i >= NN) return;
  const int base = rs[i], end = rs[i + 1];
  const int head = hl >> 2;
  const float arh = ar[i * 8 + head];
  float s0 = 0.f, s1 = 0.f;
  float a0 = 0.f, a1 = 0.f, a2 = 0.f, a3 = 0.f;
  float c0 = 0.f, c1 = 0.f, c2 = 0.f, c3 = 0.f;

  int e = base;
  for (; e + 8 <= end; e += 8) {
    int js[8];
    float ews[8], lgs[8];
    unsigned int hvs[8];
#pragma unroll
    for (int u = 0; u < 8; ++u) {
      uint2 ce = edge[e + u];
      js[u] = (int)ce.x;
      ews[u] = __uint_as_float(ce.y);
    }
#pragma unroll
    for (int u = 0; u < 8; ++u) lgs[u] = al[js[u] * 8 + head];
#pragma unroll
    for (int u = 0; u < 8; ++u) hvs[u] = h1f32[(size_t)js[u] * 32 + hl];
#pragma unroll
    for (int u = 0; u < 8; ++u) {
      float q = __expf(lrelu(lgs[u] + arh));
      float pw = q * ews[u];
      f32x2 lo = __builtin_amdgcn_cvt_pk_f32_fp8((int)hvs[u], false);
      f32x2 hi = __builtin_amdgcn_cvt_pk_f32_fp8((int)hvs[u], true);
      if (u & 1) {
        s1 += q;
        c0 = fmaf(pw, lo[0], c0);
        c1 = fmaf(pw, lo[1], c1);
        c2 = fmaf(pw, hi[0], c2);
        c3 = fmaf(pw, hi[1], c3);
      } else {
        s0 += q;
        a0 = fmaf(pw, lo[0], a0);
        a1 = fmaf(pw, lo[1], a1);
        a2 = fmaf(pw, hi[0], a2);
        a3 = fmaf(pw, hi[1], a3);
      }
    }
  }
  for (; e < end; ++e) {
    uint2 ce = edge[e];
    int j = (int)ce.x;
    float q = __expf(lrelu(al[j * 8 + head] + arh));
    unsigned int hv = h1f32[(size_t)j * 32 + hl];
    float pw = q * __uint_as_float(ce.y);
    f32x2 lo = __builtin_amdgcn_cvt_pk_f32_fp8((int)hv, false);
    f32x2 hi = __builtin_amdgcn_cvt_pk_f32_fp8((int)hv, true);
    s0 += q;
    a0 = fmaf(pw, lo[0], a0);
    a1 = fmaf(pw, lo[1], a1);
    a2 = fmaf(pw, hi[0], a2);
    a3 = fmaf(pw, hi[1], a3);
  }
  float inv = 1.f / (s0 + s1);
  float4 bias = *(const float4*)&b1[4 * hl];
  float o0 = elu(fmaf(a0 + c0, inv, bias.x));
  float o1 = elu(fmaf(a1 + c1, inv, bias.y));
  float o2 = elu(fmaf(a2 + c2, inv, bias.z));
  float o3 = elu(fmaf(a3 + c3, inv, bias.w));
  uint2 pk;
  pk.x = (unsigned int)f2bf(o0) | ((unsigned int)f2bf(o1) << 16);
  pk.y = (unsigned int)f2bf(o2) | ((unsigned int)f2bf(o3) << 16);
  h1eb[(size_t)i * 32 + hl] = pk;
}

// ---- GEMM2: hp2f[N][40] = fp8(h1e @ W2^T), 24 nodes/block, LDS repack ----
__global__ __launch_bounds__(256) void k_gemm2(const unsigned int* __restrict__ h1eb,
                                               const float* __restrict__ W2,
                                               unsigned int* __restrict__ hp2f32) {
  __shared__ float wl[40 * 132];
  __shared__ float hs[24 * 132];
  __shared__ unsigned int pk2[24 * 10];
  int t = threadIdx.x;
#pragma unroll
  for (int it = 0; it < 5; ++it) {
    int idx = t + 256 * it;
    int c = idx >> 5, k4 = (idx & 31) << 2;
    *(float4*)&wl[c * 132 + k4] = *(const float4*)&W2[c * 128 + k4];
  }
  int n0 = blockIdx.x * 24;
#pragma unroll
  for (int it = 0; it < 6; ++it) {
    int idx = t + 256 * it;
    int nl = idx >> 6, k = idx & 63;
    int n = n0 + nl;
    unsigned int hv = (n < NN) ? h1eb[(size_t)n * 64 + k] : 0u;
    hs[nl * 132 + 2 * k] = bflo(hv);
    hs[nl * 132 + 2 * k + 1] = bfhi(hv);
  }
  __syncthreads();
  unsigned char* pkb = (unsigned char*)pk2;
  for (int o = t; o < 960; o += 256) {
    int nl = o / 40, c = o - nl * 40;
    float a = 0.f;
#pragma unroll 8
    for (int k = 0; k < 128; k += 4) {
      float4 h = *(const float4*)&hs[nl * 132 + k];
      float4 w = *(const float4*)&wl[c * 132 + k];
      a = fmaf(h.x, w.x, a);
      a = fmaf(h.y, w.y, a);
      a = fmaf(h.z, w.z, a);
      a = fmaf(h.w, w.w, a);
    }
    pkb[nl * 40 + c] = f2fp8(a);
  }
  __syncthreads();
  if (t < 240) {
    size_t g = (size_t)n0 * 10 + t;
    if (g < (size_t)NN * 10) hp2f32[g] = pk2[t];
  }
}

// ---------------- per-node attention halves, layer 2 (fp8 table) ----------------
__global__ void k_alr2(const unsigned int* __restrict__ hp2f32, const float* __restrict__ attl,
                       const float* __restrict__ attr, float* __restrict__ al,
                       float* __restrict__ ar) {
  int n = blockIdx.x * 256 + threadIdx.x;
  if (n >= NN) return;
  const unsigned int* row = hp2f32 + (size_t)n * 10;
  float a = 0.f, b = 0.f;
#pragma unroll
  for (int c = 0; c < 10; ++c) {
    unsigned int u = row[c];
    f32x2 lo = __builtin_amdgcn_cvt_pk_f32_fp8((int)u, false);
    f32x2 hi = __builtin_amdgcn_cvt_pk_f32_fp8((int)u, true);
    a = fmaf(lo[0], attl[4 * c], a);
    a = fmaf(lo[1], attl[4 * c + 1], a);
    a = fmaf(hi[0], attl[4 * c + 2], a);
    a = fmaf(hi[1], attl[4 * c + 3], a);
    b = fmaf(lo[0], attr[4 * c], b);
    b = fmaf(lo[1], attr[4 * c + 1], b);
    b = fmaf(hi[0], attr[4 * c + 2], b);
    b = fmaf(hi[1], attr[4 * c + 3], b);
  }
  al[n] = a;
  ar[n] = b;
}

// ---- layer-2 attention prepass: edge.y <- q*ew (in place), sinv[i] = 1/sum(q) ----
__global__ __launch_bounds__(256) void k_qw2(const int* __restrict__ rs,
                                             uint2* __restrict__ edge,
                                             const float* __restrict__ al2,
                                             const float* __restrict__ ar2,
                                             float* __restrict__ sinv) {
  const int lane = threadIdx.x & 63;
  const int i = blockIdx.x * 4 + (threadIdx.x >> 6);
  if (i >= NN) return;
  const int base = rs[i], end = rs[i + 1];
  const float ari = ar2[i];
  float s = 0.f;
  for (int e = base + lane; e < end; e += 64) {
    uint2 ce = edge[e];
    float q = __expf(lrelu(al2[(int)ce.x] + ari));
    s += q;
    ((float*)&edge[e])[1] = q * __uint_as_float(ce.y);
  }
#pragma unroll
  for (int off = 1; off < 64; off <<= 1) s += __shfl_xor(s, off);
  if (lane == 0) sinv[i] = 1.f / s;
}

// ---- layer-2 aggregation + bias + log_softmax: 1 node/wave, pre-weighted, fp8 gather ----
__global__ __launch_bounds__(256) void k_agg2(const int* __restrict__ rs,
                                              const uint2* __restrict__ edge,
                                              const unsigned short* __restrict__ hp2f16,
                                              const float* __restrict__ sinv,
                                              const float* __restrict__ b2,
                                              float* __restrict__ out) {
  const int lane = threadIdx.x & 63;
  const int i = blockIdx.x * 4 + (threadIdx.x >> 6);
  if (i >= NN) return;
  const int base = rs[i], end = rs[i + 1];
  const int s = lane >> 5;
  const int f = lane & 31;
  float a0 = 0.f, a1 = 0.f;

  int e = base + s;
  for (; e + 2 < end; e += 4) {
    uint2 ceA = edge[e];
    uint2 ceB = edge[e + 2];
    unsigned int hA = (f < 20) ? (unsigned int)hp2f16[(size_t)ceA.x * 20 + f] : 0u;
    unsigned int hB = (f < 20) ? (unsigned int)hp2f16[(size_t)ceB.x * 20 + f] : 0u;
    float pA = __uint_as_float(ceA.y), pB = __uint_as_float(ceB.y);
    f32x2 vA = __builtin_amdgcn_cvt_pk_f32_fp8((int)hA, false);
    f32x2 vB = __builtin_amdgcn_cvt_pk_f32_fp8((int)hB, false);
    a0 = fmaf(pA, vA[0], a0);
    a1 = fmaf(pA, vA[1], a1);
    a0 = fmaf(pB, vB[0], a0);
    a1 = fmaf(pB, vB[1], a1);
  }
  if (e < end) {
    uint2 ce = edge[e];
    unsigned int hv = (f < 20) ? (unsigned int)hp2f16[(size_t)ce.x * 20 + f] : 0u;
    float p = __uint_as_float(ce.y);
    f32x2 v = __builtin_amdgcn_cvt_pk_f32_fp8((int)hv, false);
    a0 = fmaf(p, v[0], a0);
    a1 = fmaf(p, v[1], a1);
  }
  a0 += __shfl_xor(a0, 32);
  a1 += __shfl_xor(a1, 32);
  float inv = sinv[i];
  float v0 = -1e30f, v1 = -1e30f;
  if (f < 20) {
    v0 = fmaf(a0, inv, b2[2 * f]);
    v1 = fmaf(a1, inv, b2[2 * f + 1]);
  }
  float mx = fmaxf(v0, v1);
#pragma unroll
  for (int off = 1; off < 32; off <<= 1) mx = fmaxf(mx, __shfl_xor(mx, off, 32));
  float se = (f < 20) ? __expf(v0 - mx) + __expf(v1 - mx) : 0.f;
#pragma unroll
  for (int off = 1; off < 32; off <<= 1) se += __shfl_xor(se, off, 32);
  if (f < 20 && s == 0) {
    float ls = mx + __logf(se);
    ((float2*)(out + (size_t)i * 40))[f] = make_float2(v0 - ls, v1 - ls);
  }
}

extern "C" void kernel_launch(void* const* d_in, const int* in_sizes, int n_in,
                              void* d_out, int out_size, void* d_ws, size_t ws_size,
                              hipStream_t stream) {
  const float* x     = (const float*)d_in[0];
  const int*   esrc  = (const int*)d_in[1];
  const int*   edst  = (const int*)d_in[2];
  const float* ew    = (const float*)d_in[3];
  const float* W1    = (const float*)d_in[4];
  const float* attl1 = (const float*)d_in[5];
  const float* attr1 = (const float*)d_in[6];
  const float* b1    = (const float*)d_in[7];
  const float* W2    = (const float*)d_in[8];
  const float* attl2 = (const float*)d_in[9];
  const float* attr2 = (const float*)d_in[10];
  const float* b2    = (const float*)d_in[11];
  float* out = (float*)d_out;

  char* w = (char*)d_ws;
  auto take = [&](size_t bytes) {
    char* p = w;
    w += (bytes + 255) & ~(size_t)255;
    return p;
  };
  unsigned int* h1f  = (unsigned int*)take((size_t)NN * F1);       // fp8 table, 6.4 MB
  unsigned int* h1eb = (unsigned int*)take((size_t)NN * 64 * 4);   // bf16, 12.8 MB
  float* al1 = (float*)take((size_t)NN * NH * 4);
  float* ar1 = (float*)take((size_t)NN * NH * 4);
  unsigned int* hp2f = (unsigned int*)take((size_t)NN * 40);       // fp8 table, 2 MB
  float* al2 = (float*)take((size_t)NN * 4);
  float* ar2 = (float*)take((size_t)NN * 4);
  float* sinv = (float*)take((size_t)NN * 4);
  int*   rs  = (int*)take((size_t)(NN + 1) * 4);
  uint2* edge = (uint2*)take((size_t)NT * 8);
  int* bktCnt = (int*)take(NB * 4);
  int* bbase  = (int*)take(NB * 4);

  // staging aliases h1f+h1eb+al1 (20.8 MB contiguous; CSR build precedes their writers)
  uint2* bSrcEw = (uint2*)h1f;                                           // 16.06 MB
  unsigned short* bDst = (unsigned short*)((char*)h1f + (size_t)NB * BCAP * 8);  // 4.01 MB

  // CSR build (by destination), self loop = slot 0 of each segment
  hipMemsetAsync(bktCnt, 0, NB * 4, stream);
  k_binA<<<(NE + TILE - 1) / TILE, 256, 0, stream>>>(esrc, edst, ew, bktCnt, bSrcEw, bDst);
  k_bscan<<<1, 256, 0, stream>>>(bktCnt, bbase, rs);
  k_fillB<<<NB, 256, 0, stream>>>(bktCnt, bbase, bSrcEw, bDst, ew, rs, edge);

  // layer 1
  k_gemm1<<<(NN + 127) / 128, 256, 0, stream>>>(x, W1, h1f);
  k_alr1<<<(NN * NH + 255) / 256, 256, 0, stream>>>(h1f, attl1, attr1, al1, ar1);
  k_agg1<<<(NN + 7) / 8, 256, 0, stream>>>(rs, edge, h1f, al1, ar1, b1, (uint2*)h1eb);

  // layer 2
  k_gemm2<<<(NN + 23) / 24, 256, 0, stream>>>(h1eb, W2, hp2f);
  k_alr2<<<(NN + 255) / 256, 256, 0, stream>>>(hp2f, attl2, attr2, al2, ar2);
  k_qw2<<<(NN + 3) / 4, 256, 0, stream>>>(rs, edge, al2, ar2, sinv);
  k_agg2<<<(NN + 3) / 4, 256, 0, stream>>>(rs, edge, (const unsigned short*)hp2f, sinv, b2, out);
}

// Round 8
// 227.876 us; speedup vs baseline: 1.5057x; 1.0497x over previous
//
#include <hip/hip_runtime.h>

#define NN 50000
#define NE 1600000
#define NT (NE + NN)   // total edges incl self loops
#define NF 512
#define F1 128
#define NH 8
#define F2 40

#define NB 196         // dst buckets of 256 nodes
#define BCAP 10240     // per-bucket staging capacity (mean 8163, sd ~90)
#define TILE 4096

typedef __attribute__((ext_vector_type(8))) short short8;
typedef __attribute__((ext_vector_type(4))) short short4v;
typedef __attribute__((ext_vector_type(4))) float f32x4;
typedef __attribute__((ext_vector_type(2))) float f32x2;

__device__ __forceinline__ float lrelu(float x) { return fmaxf(x, 0.2f * x); }

__device__ __forceinline__ unsigned short f2bf(float f) {
  unsigned int u = __float_as_uint(f);
  u += 0x7fffu + ((u >> 16) & 1u);  // RNE
  return (unsigned short)(u >> 16);
}
__device__ __forceinline__ float bfhi(unsigned int dw) { return __uint_as_float(dw & 0xffff0000u); }
__device__ __forceinline__ float bflo(unsigned int dw) { return __uint_as_float(dw << 16); }
__device__ __forceinline__ float elu(float x) { return x > 0.f ? x : __expf(x) - 1.f; }

__device__ __forceinline__ unsigned char f2fp8(float v) {
  return (unsigned char)(__builtin_amdgcn_cvt_pk_fp8_f32(v, v, 0, false) & 0xFF);
}

// ---------------- CSR build phase A: bucket-bin edges with LDS tile sort ----------------
__global__ __launch_bounds__(256) void k_binA(const int* __restrict__ esrc,
                                              const int* __restrict__ edst,
                                              const float* __restrict__ ew,
                                              int* __restrict__ bktCnt,
                                              uint2* __restrict__ bSrcEw,
                                              unsigned short* __restrict__ bDst) {
  __shared__ int cnt[NB];
  __shared__ int scn[NB];
  __shared__ int gbase[NB];
  __shared__ int cur[NB];
  __shared__ int tmp[256];
  __shared__ uint2 stSE[TILE];
  __shared__ unsigned short stD[TILE];
  const int t = threadIdx.x;
  const int e0 = blockIdx.x * TILE;

  for (int b = t; b < NB; b += 256) cnt[b] = 0;
  __syncthreads();

  unsigned int sd[16];
  float wv[16];
#pragma unroll
  for (int u = 0; u < 16; ++u) {
    int e = e0 + t + 256 * u;
    if (e < NE) {
      unsigned int s = (unsigned int)esrc[e];
      unsigned int d = (unsigned int)edst[e];
      sd[u] = s | (d << 16);
      wv[u] = ew[e];
      atomicAdd(&cnt[d >> 8], 1);
    } else {
      sd[u] = 0xFFFFFFFFu;
    }
  }
  __syncthreads();

  int v = (t < NB) ? cnt[t] : 0;
  tmp[t] = v;
  __syncthreads();
  for (int off = 1; off < 256; off <<= 1) {
    int a = (t >= off) ? tmp[t - off] : 0;
    __syncthreads();
    tmp[t] += a;
    __syncthreads();
  }
  if (t < NB) {
    scn[t] = tmp[t] - v;
    cur[t] = tmp[t] - v;
    gbase[t] = atomicAdd(&bktCnt[t], v);
  }
  __syncthreads();

#pragma unroll
  for (int u = 0; u < 16; ++u) {
    if (sd[u] != 0xFFFFFFFFu) {
      unsigned int d = sd[u] >> 16;
      int p = atomicAdd(&cur[d >> 8], 1);
      stSE[p] = make_uint2(sd[u] & 0xFFFFu, __float_as_uint(wv[u]));
      stD[p] = (unsigned short)d;
    }
  }
  __syncthreads();

  int tot = NE - e0;
  if (tot > TILE) tot = TILE;
  for (int k = t; k < tot; k += 256) {
    int d = stD[k];
    int b = d >> 8;
    int idx = gbase[b] + (k - scn[b]);
    bSrcEw[(size_t)b * BCAP + idx] = stSE[k];
    bDst[(size_t)b * BCAP + idx] = (unsigned short)d;
  }
}

// ---------------- CSR build: scan bucket totals (incl self loops) ----------------
__global__ void k_bscan(const int* __restrict__ bktCnt, int* __restrict__ base,
                        int* __restrict__ rs) {
  __shared__ int tmp[256];
  int t = threadIdx.x;
  int nInB = 0;
  if (t < NB) nInB = (t == NB - 1) ? (NN - (NB - 1) * 256) : 256;
  int v = (t < NB) ? bktCnt[t] + nInB : 0;
  tmp[t] = v;
  __syncthreads();
  for (int off = 1; off < 256; off <<= 1) {
    int a = (t >= off) ? tmp[t - off] : 0;
    __syncthreads();
    tmp[t] += a;
    __syncthreads();
  }
  if (t < NB) base[t] = tmp[t] - v;
  if (t == 0) rs[NN] = NT;
}

// ---------------- CSR build phase B: per-bucket local hist/scan/scatter ----------------
__global__ __launch_bounds__(256) void k_fillB(const int* __restrict__ bktCnt,
                                               const int* __restrict__ base,
                                               const uint2* __restrict__ bSrcEw,
                                               const unsigned short* __restrict__ bDst,
                                               const float* __restrict__ ew,
                                               int* __restrict__ rs,
                                               uint2* __restrict__ edge) {
  __shared__ int cnt[256], cur[256], tmp[256];
  const int b = blockIdx.x, t = threadIdx.x;
  const int n0 = b * 256;
  const int nNodes = (n0 + 256 <= NN) ? 256 : (NN - n0);
  const int cE = bktCnt[b];
  const int gb = base[b];

  cnt[t] = 0;
  __syncthreads();
  for (int k = t; k < cE; k += 256) atomicAdd(&cnt[bDst[(size_t)b * BCAP + k] & 255], 1);
  __syncthreads();

  int v = (t < nNodes) ? cnt[t] + 1 : 0;  // +1 self loop
  tmp[t] = v;
  __syncthreads();
  for (int off = 1; off < 256; off <<= 1) {
    int a = (t >= off) ? tmp[t - off] : 0;
    __syncthreads();
    tmp[t] += a;
    __syncthreads();
  }
  int off_ = tmp[t] - v;  // exclusive
  if (t < nNodes) {
    rs[n0 + t] = gb + off_;
    cur[t] = off_ + 1;  // slot 0 = self loop
    edge[(size_t)gb + off_] = make_uint2((unsigned int)(n0 + t), __float_as_uint(ew[NE + n0 + t]));
  }
  __syncthreads();

  for (int k = t; k < cE; k += 256) {
    uint2 se = bSrcEw[(size_t)b * BCAP + k];
    int d = bDst[(size_t)b * BCAP + k] & 255;
    int p = atomicAdd(&cur[d], 1);
    edge[(size_t)gb + p] = se;
  }
}

// ---------------- W1 fp32 -> bf16 prepass (128x512) ----------------
__global__ void k_w1bf(const float* __restrict__ W1, unsigned short* __restrict__ W1b) {
  int i = blockIdx.x * 256 + threadIdx.x;  // one float4 each; 16384 total
  if (i < 16384) {
    float4 v = ((const float4*)W1)[i];
    short4v b;
    b[0] = (short)f2bf(v.x); b[1] = (short)f2bf(v.y);
    b[2] = (short)f2bf(v.z); b[3] = (short)f2bf(v.w);
    *(short4v*)&W1b[(size_t)i * 4] = b;
  }
}

// ---- GEMM1 (MFMA bf16): h1f[N][128] = fp8(x @ W1^T); BM=32, BK=64; fused alr1 ----
__global__ __launch_bounds__(256) void k_gemm1(const float* __restrict__ x,
                                               const unsigned short* __restrict__ W1b,
                                               const float* __restrict__ attl,
                                               const float* __restrict__ attr,
                                               unsigned int* __restrict__ h1f32,
                                               float* __restrict__ al,
                                               float* __restrict__ ar) {
  __shared__ unsigned short As[32 * 72];    // 4.6 KB
  __shared__ unsigned short Bs[128 * 72];   // 18.4 KB
  __shared__ unsigned int pk32[32 * 32];    // 4 KB fp8 repack
  const int t = threadIdx.x;
  const int w = t >> 6, lane = t & 63;
  const int g16 = lane >> 4, r16 = lane & 15;
  const int m0 = blockIdx.x * 32;
  const int r0 = (w & 1) * 16;   // wave rows
  const int c0 = (w >> 1) * 64;  // wave cols

  f32x4 acc[4];
#pragma unroll
  for (int b = 0; b < 4; ++b) acc[b] = (f32x4){0.f, 0.f, 0.f, 0.f};

  for (int kc = 0; kc < NF; kc += 64) {
    __syncthreads();
#pragma unroll
    for (int i = 0; i < 2; ++i) {
      int idx = t + 256 * i;      // 0..511
      int row = idx >> 4;         // 0..31
      int k4 = (idx & 15) << 2;   // 0..60
      int n = m0 + row;
      float4 v = make_float4(0.f, 0.f, 0.f, 0.f);
      if (n < NN) v = *(const float4*)&x[(size_t)n * NF + kc + k4];
      short4v b;
      b[0] = (short)f2bf(v.x); b[1] = (short)f2bf(v.y);
      b[2] = (short)f2bf(v.z); b[3] = (short)f2bf(v.w);
      *(short4v*)&As[row * 72 + k4] = b;
    }
#pragma unroll
    for (int i = 0; i < 4; ++i) {
      int idx = t + 256 * i;      // 0..1023
      int col = idx >> 3;         // 0..127
      int k8 = (idx & 7) << 3;    // 0..56
      *(short8*)&Bs[col * 72 + k8] = *(const short8*)&W1b[(size_t)col * NF + kc + k8];
    }
    __syncthreads();

    short8 afr[2], bfr[4][2];
#pragma unroll
    for (int ks = 0; ks < 2; ++ks)
      afr[ks] = *(const short8*)&As[(r0 + r16) * 72 + ks * 32 + g16 * 8];
#pragma unroll
    for (int nj = 0; nj < 4; ++nj)
#pragma unroll
      for (int ks = 0; ks < 2; ++ks)
        bfr[nj][ks] = *(const short8*)&Bs[(c0 + nj * 16 + r16) * 72 + ks * 32 + g16 * 8];
#pragma unroll
    for (int nj = 0; nj < 4; ++nj)
#pragma unroll
      for (int ks = 0; ks < 2; ++ks)
        acc[nj] = __builtin_amdgcn_mfma_f32_16x16x32_bf16(afr[ks], bfr[nj][ks], acc[nj], 0, 0, 0);
  }

  // fp8-pack into LDS
  unsigned char* pkb = (unsigned char*)pk32;
  __syncthreads();
#pragma unroll
  for (int nj = 0; nj < 4; ++nj)
#pragma unroll
    for (int r = 0; r < 4; ++r)
      pkb[(r0 + g16 * 4 + r) * 128 + c0 + nj * 16 + r16] = f2fp8(acc[nj][r]);
  __syncthreads();

  // coalesced store: 32 rows x 8 uint4 = 256 threads
  {
    int row = t >> 3, q = t & 7;
    int n = m0 + row;
    if (n < NN) ((uint4*)h1f32)[(size_t)n * 8 + q] = ((const uint4*)pk32)[row * 8 + q];
  }
  // fused alr1: thread -> (row=t>>3, head=t&7)
  {
    int row = t >> 3, h = t & 7;
    int n = m0 + row;
    if (n < NN) {
      float a = 0.f, b = 0.f;
#pragma unroll
      for (int c = 0; c < 4; ++c) {
        unsigned int u = pk32[row * 32 + h * 4 + c];
        f32x2 lo = __builtin_amdgcn_cvt_pk_f32_fp8((int)u, false);
        f32x2 hi = __builtin_amdgcn_cvt_pk_f32_fp8((int)u, true);
        int f0 = h * 16 + 4 * c;
        a = fmaf(lo[0], attl[f0], a);
        a = fmaf(lo[1], attl[f0 + 1], a);
        a = fmaf(hi[0], attl[f0 + 2], a);
        a = fmaf(hi[1], attl[f0 + 3], a);
        b = fmaf(lo[0], attr[f0], b);
        b = fmaf(lo[1], attr[f0 + 1], b);
        b = fmaf(hi[0], attr[f0 + 2], b);
        b = fmaf(hi[1], attr[f0 + 3], b);
      }
      al[n * 8 + h] = a;
      ar[n * 8 + h] = b;
    }
  }
}

// ---- layer-1 aggregation: 2 nodes/wave (32-lane halves), plain exp, fp8 gather ----
__global__ __launch_bounds__(256) void k_agg1(const int* __restrict__ rs,
                                              const uint2* __restrict__ edge,
                                              const unsigned int* __restrict__ h1f32,
                                              const float* __restrict__ al,
                                              const float* __restrict__ ar,
                                              const float* __restrict__ b1,
                                              uint2* __restrict__ h1eb) {
  const int hl = threadIdx.x & 31;
  const int i = blockIdx.x * 8 + (threadIdx.x >> 5);
  if (i >= NN) return;
  const int base = rs[i], end = rs[i + 1];
  const int head = hl >> 2;
  const float arh = ar[i * 8 + head];
  float s0 = 0.f, s1 = 0.f;
  float a0 = 0.f, a1 = 0.f, a2 = 0.f, a3 = 0.f;
  float c0 = 0.f, c1 = 0.f, c2 = 0.f, c3 = 0.f;

  int e = base;
  for (; e + 8 <= end; e += 8) {
    int js[8];
    float ews[8], lgs[8];
    unsigned int hvs[8];
#pragma unroll
    for (int u = 0; u < 8; ++u) {
      uint2 ce = edge[e + u];
      js[u] = (int)ce.x;
      ews[u] = __uint_as_float(ce.y);
    }
#pragma unroll
    for (int u = 0; u < 8; ++u) lgs[u] = al[js[u] * 8 + head];
#pragma unroll
    for (int u = 0; u < 8; ++u) hvs[u] = h1f32[(size_t)js[u] * 32 + hl];
#pragma unroll
    for (int u = 0; u < 8; ++u) {
      float q = __expf(lrelu(lgs[u] + arh));
      float pw = q * ews[u];
      f32x2 lo = __builtin_amdgcn_cvt_pk_f32_fp8((int)hvs[u], false);
      f32x2 hi = __builtin_amdgcn_cvt_pk_f32_fp8((int)hvs[u], true);
      if (u & 1) {
        s1 += q;
        c0 = fmaf(pw, lo[0], c0);
        c1 = fmaf(pw, lo[1], c1);
        c2 = fmaf(pw, hi[0], c2);
        c3 = fmaf(pw, hi[1], c3);
      } else {
        s0 += q;
        a0 = fmaf(pw, lo[0], a0);
        a1 = fmaf(pw, lo[1], a1);
        a2 = fmaf(pw, hi[0], a2);
        a3 = fmaf(pw, hi[1], a3);
      }
    }
  }
  for (; e < end; ++e) {
    uint2 ce = edge[e];
    int j = (int)ce.x;
    float q = __expf(lrelu(al[j * 8 + head] + arh));
    unsigned int hv = h1f32[(size_t)j * 32 + hl];
    float pw = q * __uint_as_float(ce.y);
    f32x2 lo = __builtin_amdgcn_cvt_pk_f32_fp8((int)hv, false);
    f32x2 hi = __builtin_amdgcn_cvt_pk_f32_fp8((int)hv, true);
    s0 += q;
    a0 = fmaf(pw, lo[0], a0);
    a1 = fmaf(pw, lo[1], a1);
    a2 = fmaf(pw, hi[0], a2);
    a3 = fmaf(pw, hi[1], a3);
  }
  float inv = 1.f / (s0 + s1);
  float4 bias = *(const float4*)&b1[4 * hl];
  float o0 = elu(fmaf(a0 + c0, inv, bias.x));
  float o1 = elu(fmaf(a1 + c1, inv, bias.y));
  float o2 = elu(fmaf(a2 + c2, inv, bias.z));
  float o3 = elu(fmaf(a3 + c3, inv, bias.w));
  uint2 pk;
  pk.x = (unsigned int)f2bf(o0) | ((unsigned int)f2bf(o1) << 16);
  pk.y = (unsigned int)f2bf(o2) | ((unsigned int)f2bf(o3) << 16);
  h1eb[(size_t)i * 32 + hl] = pk;
}

// ---- GEMM2: hp2f[N][40] = fp8(h1e @ W2^T), 24 nodes/block, LDS repack ----
__global__ __launch_bounds__(256) void k_gemm2(const unsigned int* __restrict__ h1eb,
                                               const float* __restrict__ W2,
                                               unsigned int* __restrict__ hp2f32) {
  __shared__ float wl[40 * 132];
  __shared__ float hs[24 * 132];
  __shared__ unsigned int pk2[24 * 10];
  int t = threadIdx.x;
#pragma unroll
  for (int it = 0; it < 5; ++it) {
    int idx = t + 256 * it;
    int c = idx >> 5, k4 = (idx & 31) << 2;
    *(float4*)&wl[c * 132 + k4] = *(const float4*)&W2[c * 128 + k4];
  }
  int n0 = blockIdx.x * 24;
#pragma unroll
  for (int it = 0; it < 6; ++it) {
    int idx = t + 256 * it;
    int nl = idx >> 6, k = idx & 63;
    int n = n0 + nl;
    unsigned int hv = (n < NN) ? h1eb[(size_t)n * 64 + k] : 0u;
    hs[nl * 132 + 2 * k] = bflo(hv);
    hs[nl * 132 + 2 * k + 1] = bfhi(hv);
  }
  __syncthreads();
  unsigned char* pkb = (unsigned char*)pk2;
  for (int o = t; o < 960; o += 256) {
    int nl = o / 40, c = o - nl * 40;
    float a = 0.f;
#pragma unroll 8
    for (int k = 0; k < 128; k += 4) {
      float4 h = *(const float4*)&hs[nl * 132 + k];
      float4 w = *(const float4*)&wl[c * 132 + k];
      a = fmaf(h.x, w.x, a);
      a = fmaf(h.y, w.y, a);
      a = fmaf(h.z, w.z, a);
      a = fmaf(h.w, w.w, a);
    }
    pkb[nl * 40 + c] = f2fp8(a);
  }
  __syncthreads();
  if (t < 240) {
    size_t g = (size_t)n0 * 10 + t;
    if (g < (size_t)NN * 10) hp2f32[g] = pk2[t];
  }
}

// ---------------- per-node attention halves, layer 2 (fp8 table) ----------------
__global__ void k_alr2(const unsigned int* __restrict__ hp2f32, const float* __restrict__ attl,
                       const float* __restrict__ attr, float* __restrict__ al,
                       float* __restrict__ ar) {
  int n = blockIdx.x * 256 + threadIdx.x;
  if (n >= NN) return;
  const unsigned int* row = hp2f32 + (size_t)n * 10;
  float a = 0.f, b = 0.f;
#pragma unroll
  for (int c = 0; c < 10; ++c) {
    unsigned int u = row[c];
    f32x2 lo = __builtin_amdgcn_cvt_pk_f32_fp8((int)u, false);
    f32x2 hi = __builtin_amdgcn_cvt_pk_f32_fp8((int)u, true);
    a = fmaf(lo[0], attl[4 * c], a);
    a = fmaf(lo[1], attl[4 * c + 1], a);
    a = fmaf(hi[0], attl[4 * c + 2], a);
    a = fmaf(hi[1], attl[4 * c + 3], a);
    b = fmaf(lo[0], attr[4 * c], b);
    b = fmaf(lo[1], attr[4 * c + 1], b);
    b = fmaf(hi[0], attr[4 * c + 2], b);
    b = fmaf(hi[1], attr[4 * c + 3], b);
  }
  al[n] = a;
  ar[n] = b;
}

// ---- layer-2 attention prepass: edge.y <- q*ew (in place), sinv[i] = 1/sum(q) ----
__global__ __launch_bounds__(256) void k_qw2(const int* __restrict__ rs,
                                             uint2* __restrict__ edge,
                                             const float* __restrict__ al2,
                                             const float* __restrict__ ar2,
                                             float* __restrict__ sinv) {
  const int lane = threadIdx.x & 63;
  const int i = blockIdx.x * 4 + (threadIdx.x >> 6);
  if (i >= NN) return;
  const int base = rs[i], end = rs[i + 1];
  const float ari = ar2[i];
  float s = 0.f;
  for (int e = base + lane; e < end; e += 64) {
    uint2 ce = edge[e];
    float q = __expf(lrelu(al2[(int)ce.x] + ari));
    s += q;
    ((float*)&edge[e])[1] = q * __uint_as_float(ce.y);
  }
#pragma unroll
  for (int off = 1; off < 64; off <<= 1) s += __shfl_xor(s, off);
  if (lane == 0) sinv[i] = 1.f / s;
}

// ---- layer-2 aggregation + bias + log_softmax: 1 node/wave, pre-weighted, fp8 gather ----
__global__ __launch_bounds__(256) void k_agg2(const int* __restrict__ rs,
                                              const uint2* __restrict__ edge,
                                              const unsigned short* __restrict__ hp2f16,
                                              const float* __restrict__ sinv,
                                              const float* __restrict__ b2,
                                              float* __restrict__ out) {
  const int lane = threadIdx.x & 63;
  const int i = blockIdx.x * 4 + (threadIdx.x >> 6);
  if (i >= NN) return;
  const int base = rs[i], end = rs[i + 1];
  const int s = lane >> 5;
  const int f = lane & 31;
  float a0 = 0.f, a1 = 0.f;

  int e = base + s;
  for (; e + 2 < end; e += 4) {
    uint2 ceA = edge[e];
    uint2 ceB = edge[e + 2];
    unsigned int hA = (f < 20) ? (unsigned int)hp2f16[(size_t)ceA.x * 20 + f] : 0u;
    unsigned int hB = (f < 20) ? (unsigned int)hp2f16[(size_t)ceB.x * 20 + f] : 0u;
    float pA = __uint_as_float(ceA.y), pB = __uint_as_float(ceB.y);
    f32x2 vA = __builtin_amdgcn_cvt_pk_f32_fp8((int)hA, false);
    f32x2 vB = __builtin_amdgcn_cvt_pk_f32_fp8((int)hB, false);
    a0 = fmaf(pA, vA[0], a0);
    a1 = fmaf(pA, vA[1], a1);
    a0 = fmaf(pB, vB[0], a0);
    a1 = fmaf(pB, vB[1], a1);
  }
  if (e < end) {
    uint2 ce = edge[e];
    unsigned int hv = (f < 20) ? (unsigned int)hp2f16[(size_t)ce.x * 20 + f] : 0u;
    float p = __uint_as_float(ce.y);
    f32x2 v = __builtin_amdgcn_cvt_pk_f32_fp8((int)hv, false);
    a0 = fmaf(p, v[0], a0);
    a1 = fmaf(p, v[1], a1);
  }
  a0 += __shfl_xor(a0, 32);
  a1 += __shfl_xor(a1, 32);
  float inv = sinv[i];
  float v0 = -1e30f, v1 = -1e30f;
  if (f < 20) {
    v0 = fmaf(a0, inv, b2[2 * f]);
    v1 = fmaf(a1, inv, b2[2 * f + 1]);
  }
  float mx = fmaxf(v0, v1);
#pragma unroll
  for (int off = 1; off < 32; off <<= 1) mx = fmaxf(mx, __shfl_xor(mx, off, 32));
  float se = (f < 20) ? __expf(v0 - mx) + __expf(v1 - mx) : 0.f;
#pragma unroll
  for (int off = 1; off < 32; off <<= 1) se += __shfl_xor(se, off, 32);
  if (f < 20 && s == 0) {
    float ls = mx + __logf(se);
    ((float2*)(out + (size_t)i * 40))[f] = make_float2(v0 - ls, v1 - ls);
  }
}

extern "C" void kernel_launch(void* const* d_in, const int* in_sizes, int n_in,
                              void* d_out, int out_size, void* d_ws, size_t ws_size,
                              hipStream_t stream) {
  const float* x     = (const float*)d_in[0];
  const int*   esrc  = (const int*)d_in[1];
  const int*   edst  = (const int*)d_in[2];
  const float* ew    = (const float*)d_in[3];
  const float* W1    = (const float*)d_in[4];
  const float* attl1 = (const float*)d_in[5];
  const float* attr1 = (const float*)d_in[6];
  const float* b1    = (const float*)d_in[7];
  const float* W2    = (const float*)d_in[8];
  const float* attl2 = (const float*)d_in[9];
  const float* attr2 = (const float*)d_in[10];
  const float* b2    = (const float*)d_in[11];
  float* out = (float*)d_out;

  char* w = (char*)d_ws;
  auto take = [&](size_t bytes) {
    char* p = w;
    w += (bytes + 255) & ~(size_t)255;
    return p;
  };
  unsigned int* h1f  = (unsigned int*)take((size_t)NN * F1);       // fp8 table, 6.4 MB
  unsigned int* h1eb = (unsigned int*)take((size_t)NN * 64 * 4);   // bf16, 12.8 MB
  float* al1 = (float*)take((size_t)NN * NH * 4);
  float* ar1 = (float*)take((size_t)NN * NH * 4);
  unsigned int* hp2f = (unsigned int*)take((size_t)NN * 40);       // fp8 table, 2 MB
  float* al2 = (float*)take((size_t)NN * 4);
  float* ar2 = (float*)take((size_t)NN * 4);
  float* sinv = (float*)take((size_t)NN * 4);
  int*   rs  = (int*)take((size_t)(NN + 1) * 4);
  uint2* edge = (uint2*)take((size_t)NT * 8);
  unsigned short* W1b = (unsigned short*)take((size_t)F1 * NF * 2); // 128 KB bf16 W1
  int* bktCnt = (int*)take(NB * 4);
  int* bbase  = (int*)take(NB * 4);

  // staging aliases h1f+h1eb (20 MB contiguous; CSR build precedes their writers)
  uint2* bSrcEw = (uint2*)h1f;                                           // 16.06 MB
  unsigned short* bDst = (unsigned short*)((char*)h1f + (size_t)NB * BCAP * 8);  // 4.01 MB

  // CSR build (by destination), self loop = slot 0 of each segment
  hipMemsetAsync(bktCnt, 0, NB * 4, stream);
  k_binA<<<(NE + TILE - 1) / TILE, 256, 0, stream>>>(esrc, edst, ew, bktCnt, bSrcEw, bDst);
  k_bscan<<<1, 256, 0, stream>>>(bktCnt, bbase, rs);
  k_fillB<<<NB, 256, 0, stream>>>(bktCnt, bbase, bSrcEw, bDst, ew, rs, edge);

  // layer 1
  k_w1bf<<<64, 256, 0, stream>>>(W1, W1b);
  k_gemm1<<<(NN + 31) / 32, 256, 0, stream>>>(x, W1b, attl1, attr1, h1f, al1, ar1);
  k_agg1<<<(NN + 7) / 8, 256, 0, stream>>>(rs, edge, h1f, al1, ar1, b1, (uint2*)h1eb);

  // layer 2
  k_gemm2<<<(NN + 23) / 24, 256, 0, stream>>>(h1eb, W2, hp2f);
  k_alr2<<<(NN + 255) / 256, 256, 0, stream>>>(hp2f, attl2, attr2, al2, ar2);
  k_qw2<<<(NN + 3) / 4, 256, 0, stream>>>(rs, edge, al2, ar2, sinv);
  k_agg2<<<(NN + 3) / 4, 256, 0, stream>>>(rs, edge, (const unsigned short*)hp2f, sinv, b2, out);
}

// Round 9
// 211.572 us; speedup vs baseline: 1.6217x; 1.0771x over previous
//
#include <hip/hip_runtime.h>

#define NN 50000
#define NE 1600000
#define NT (NE + NN)   // total edges incl self loops
#define NF 512
#define F1 128
#define NH 8
#define F2 40

#define NB 196         // dst buckets of 256 nodes
#define BCAP 10240     // per-bucket staging capacity (mean 8163, sd ~90)
#define TILE 4096

typedef __attribute__((ext_vector_type(8))) short short8;
typedef __attribute__((ext_vector_type(4))) short short4v;
typedef __attribute__((ext_vector_type(4))) float f32x4;
typedef __attribute__((ext_vector_type(2))) float f32x2;

__device__ __forceinline__ float lrelu(float x) { return fmaxf(x, 0.2f * x); }

__device__ __forceinline__ unsigned short f2bf(float f) {
  unsigned int u = __float_as_uint(f);
  u += 0x7fffu + ((u >> 16) & 1u);  // RNE
  return (unsigned short)(u >> 16);
}
__device__ __forceinline__ float bfhi(unsigned int dw) { return __uint_as_float(dw & 0xffff0000u); }
__device__ __forceinline__ float bflo(unsigned int dw) { return __uint_as_float(dw << 16); }
__device__ __forceinline__ float elu(float x) { return x > 0.f ? x : __expf(x) - 1.f; }

__device__ __forceinline__ unsigned char f2fp8(float v) {
  return (unsigned char)(__builtin_amdgcn_cvt_pk_fp8_f32(v, v, 0, false) & 0xFF);
}

// ---------------- CSR build phase A: bucket-bin edges with LDS tile sort ----------------
__global__ __launch_bounds__(256) void k_binA(const int* __restrict__ esrc,
                                              const int* __restrict__ edst,
                                              const float* __restrict__ ew,
                                              int* __restrict__ bktCnt,
                                              uint2* __restrict__ bSrcEw,
                                              unsigned short* __restrict__ bDst) {
  __shared__ int cnt[NB];
  __shared__ int scn[NB];
  __shared__ int gbase[NB];
  __shared__ int cur[NB];
  __shared__ int tmp[256];
  __shared__ uint2 stSE[TILE];
  __shared__ unsigned short stD[TILE];
  const int t = threadIdx.x;
  const int e0 = blockIdx.x * TILE;

  for (int b = t; b < NB; b += 256) cnt[b] = 0;
  __syncthreads();

  unsigned int sd[16];
  float wv[16];
#pragma unroll
  for (int u = 0; u < 16; ++u) {
    int e = e0 + t + 256 * u;
    if (e < NE) {
      unsigned int s = (unsigned int)esrc[e];
      unsigned int d = (unsigned int)edst[e];
      sd[u] = s | (d << 16);
      wv[u] = ew[e];
      atomicAdd(&cnt[d >> 8], 1);
    } else {
      sd[u] = 0xFFFFFFFFu;
    }
  }
  __syncthreads();

  int v = (t < NB) ? cnt[t] : 0;
  tmp[t] = v;
  __syncthreads();
  for (int off = 1; off < 256; off <<= 1) {
    int a = (t >= off) ? tmp[t - off] : 0;
    __syncthreads();
    tmp[t] += a;
    __syncthreads();
  }
  if (t < NB) {
    scn[t] = tmp[t] - v;
    cur[t] = tmp[t] - v;
    gbase[t] = atomicAdd(&bktCnt[t], v);
  }
  __syncthreads();

#pragma unroll
  for (int u = 0; u < 16; ++u) {
    if (sd[u] != 0xFFFFFFFFu) {
      unsigned int d = sd[u] >> 16;
      int p = atomicAdd(&cur[d >> 8], 1);
      stSE[p] = make_uint2(sd[u] & 0xFFFFu, __float_as_uint(wv[u]));
      stD[p] = (unsigned short)d;
    }
  }
  __syncthreads();

  int tot = NE - e0;
  if (tot > TILE) tot = TILE;
  for (int k = t; k < tot; k += 256) {
    int d = stD[k];
    int b = d >> 8;
    int idx = gbase[b] + (k - scn[b]);
    bSrcEw[(size_t)b * BCAP + idx] = stSE[k];
    bDst[(size_t)b * BCAP + idx] = (unsigned short)d;
  }
}

// ---------------- CSR build: scan bucket totals (incl self loops) ----------------
__global__ void k_bscan(const int* __restrict__ bktCnt, int* __restrict__ base,
                        int* __restrict__ rs) {
  __shared__ int tmp[256];
  int t = threadIdx.x;
  int nInB = 0;
  if (t < NB) nInB = (t == NB - 1) ? (NN - (NB - 1) * 256) : 256;
  int v = (t < NB) ? bktCnt[t] + nInB : 0;
  tmp[t] = v;
  __syncthreads();
  for (int off = 1; off < 256; off <<= 1) {
    int a = (t >= off) ? tmp[t - off] : 0;
    __syncthreads();
    tmp[t] += a;
    __syncthreads();
  }
  if (t < NB) base[t] = tmp[t] - v;
  if (t == 0) rs[NN] = NT;
}

// ---------------- CSR build phase B: per-bucket local hist/scan/scatter ----------------
__global__ __launch_bounds__(256) void k_fillB(const int* __restrict__ bktCnt,
                                               const int* __restrict__ base,
                                               const uint2* __restrict__ bSrcEw,
                                               const unsigned short* __restrict__ bDst,
                                               const float* __restrict__ ew,
                                               int* __restrict__ rs,
                                               uint2* __restrict__ edge) {
  __shared__ int cnt[256], cur[256], tmp[256];
  const int b = blockIdx.x, t = threadIdx.x;
  const int n0 = b * 256;
  const int nNodes = (n0 + 256 <= NN) ? 256 : (NN - n0);
  const int cE = bktCnt[b];
  const int gb = base[b];

  cnt[t] = 0;
  __syncthreads();
  for (int k = t; k < cE; k += 256) atomicAdd(&cnt[bDst[(size_t)b * BCAP + k] & 255], 1);
  __syncthreads();

  int v = (t < nNodes) ? cnt[t] + 1 : 0;  // +1 self loop
  tmp[t] = v;
  __syncthreads();
  for (int off = 1; off < 256; off <<= 1) {
    int a = (t >= off) ? tmp[t - off] : 0;
    __syncthreads();
    tmp[t] += a;
    __syncthreads();
  }
  int off_ = tmp[t] - v;  // exclusive
  if (t < nNodes) {
    rs[n0 + t] = gb + off_;
    cur[t] = off_ + 1;  // slot 0 = self loop
    edge[(size_t)gb + off_] = make_uint2((unsigned int)(n0 + t), __float_as_uint(ew[NE + n0 + t]));
  }
  __syncthreads();

  for (int k = t; k < cE; k += 256) {
    uint2 se = bSrcEw[(size_t)b * BCAP + k];
    int d = bDst[(size_t)b * BCAP + k] & 255;
    int p = atomicAdd(&cur[d], 1);
    edge[(size_t)gb + p] = se;
  }
}

// ---------------- W1 fp32 -> bf16 prepass (128x512) ----------------
__global__ void k_w1bf(const float* __restrict__ W1, unsigned short* __restrict__ W1b) {
  int i = blockIdx.x * 256 + threadIdx.x;  // one float4 each; 16384 total
  if (i < 16384) {
    float4 v = ((const float4*)W1)[i];
    short4v b;
    b[0] = (short)f2bf(v.x); b[1] = (short)f2bf(v.y);
    b[2] = (short)f2bf(v.z); b[3] = (short)f2bf(v.w);
    *(short4v*)&W1b[(size_t)i * 4] = b;
  }
}

// ---- GEMM1 (MFMA bf16): h1f[N][128] = fp8(x @ W1^T); BM=32, BK=64; fused alr1 ----
__global__ __launch_bounds__(256) void k_gemm1(const float* __restrict__ x,
                                               const unsigned short* __restrict__ W1b,
                                               const float* __restrict__ attl,
                                               const float* __restrict__ attr,
                                               unsigned int* __restrict__ h1f32,
                                               float* __restrict__ al,
                                               float* __restrict__ ar) {
  __shared__ unsigned short As[32 * 72];    // 4.6 KB
  __shared__ unsigned short Bs[128 * 72];   // 18.4 KB
  __shared__ unsigned int pk32[32 * 32];    // 4 KB fp8 repack
  const int t = threadIdx.x;
  const int w = t >> 6, lane = t & 63;
  const int g16 = lane >> 4, r16 = lane & 15;
  const int m0 = blockIdx.x * 32;
  const int r0 = (w & 1) * 16;   // wave rows
  const int c0 = (w >> 1) * 64;  // wave cols

  f32x4 acc[4];
#pragma unroll
  for (int b = 0; b < 4; ++b) acc[b] = (f32x4){0.f, 0.f, 0.f, 0.f};

  for (int kc = 0; kc < NF; kc += 64) {
    __syncthreads();
#pragma unroll
    for (int i = 0; i < 2; ++i) {
      int idx = t + 256 * i;      // 0..511
      int row = idx >> 4;         // 0..31
      int k4 = (idx & 15) << 2;   // 0..60
      int n = m0 + row;
      float4 v = make_float4(0.f, 0.f, 0.f, 0.f);
      if (n < NN) v = *(const float4*)&x[(size_t)n * NF + kc + k4];
      short4v b;
      b[0] = (short)f2bf(v.x); b[1] = (short)f2bf(v.y);
      b[2] = (short)f2bf(v.z); b[3] = (short)f2bf(v.w);
      *(short4v*)&As[row * 72 + k4] = b;
    }
#pragma unroll
    for (int i = 0; i < 4; ++i) {
      int idx = t + 256 * i;      // 0..1023
      int col = idx >> 3;         // 0..127
      int k8 = (idx & 7) << 3;    // 0..56
      *(short8*)&Bs[col * 72 + k8] = *(const short8*)&W1b[(size_t)col * NF + kc + k8];
    }
    __syncthreads();

    short8 afr[2], bfr[4][2];
#pragma unroll
    for (int ks = 0; ks < 2; ++ks)
      afr[ks] = *(const short8*)&As[(r0 + r16) * 72 + ks * 32 + g16 * 8];
#pragma unroll
    for (int nj = 0; nj < 4; ++nj)
#pragma unroll
      for (int ks = 0; ks < 2; ++ks)
        bfr[nj][ks] = *(const short8*)&Bs[(c0 + nj * 16 + r16) * 72 + ks * 32 + g16 * 8];
#pragma unroll
    for (int nj = 0; nj < 4; ++nj)
#pragma unroll
      for (int ks = 0; ks < 2; ++ks)
        acc[nj] = __builtin_amdgcn_mfma_f32_16x16x32_bf16(afr[ks], bfr[nj][ks], acc[nj], 0, 0, 0);
  }

  // fp8-pack into LDS
  unsigned char* pkb = (unsigned char*)pk32;
  __syncthreads();
#pragma unroll
  for (int nj = 0; nj < 4; ++nj)
#pragma unroll
    for (int r = 0; r < 4; ++r)
      pkb[(r0 + g16 * 4 + r) * 128 + c0 + nj * 16 + r16] = f2fp8(acc[nj][r]);
  __syncthreads();

  // coalesced store: 32 rows x 8 uint4 = 256 threads
  {
    int row = t >> 3, q = t & 7;
    int n = m0 + row;
    if (n < NN) ((uint4*)h1f32)[(size_t)n * 8 + q] = ((const uint4*)pk32)[row * 8 + q];
  }
  // fused alr1: thread -> (row=t>>3, head=t&7)
  {
    int row = t >> 3, h = t & 7;
    int n = m0 + row;
    if (n < NN) {
      float a = 0.f, b = 0.f;
#pragma unroll
      for (int c = 0; c < 4; ++c) {
        unsigned int u = pk32[row * 32 + h * 4 + c];
        f32x2 lo = __builtin_amdgcn_cvt_pk_f32_fp8((int)u, false);
        f32x2 hi = __builtin_amdgcn_cvt_pk_f32_fp8((int)u, true);
        int f0 = h * 16 + 4 * c;
        a = fmaf(lo[0], attl[f0], a);
        a = fmaf(lo[1], attl[f0 + 1], a);
        a = fmaf(hi[0], attl[f0 + 2], a);
        a = fmaf(hi[1], attl[f0 + 3], a);
        b = fmaf(lo[0], attr[f0], b);
        b = fmaf(lo[1], attr[f0 + 1], b);
        b = fmaf(hi[0], attr[f0 + 2], b);
        b = fmaf(hi[1], attr[f0 + 3], b);
      }
      al[n * 8 + h] = a;
      ar[n * 8 + h] = b;
    }
  }
}

// ---- layer-1 aggregation: 2 nodes/wave (32-lane halves), plain exp, fp8 gather ----
__global__ __launch_bounds__(256) void k_agg1(const int* __restrict__ rs,
                                              const uint2* __restrict__ edge,
                                              const unsigned int* __restrict__ h1f32,
                                              const float* __restrict__ al,
                                              const float* __restrict__ ar,
                                              const float* __restrict__ b1,
                                              uint2* __restrict__ h1eb) {
  const int hl = threadIdx.x & 31;
  const int i = blockIdx.x * 8 + (threadIdx.x >> 5);
  if (i >= NN) return;
  const int base = rs[i], end = rs[i + 1];
  const int head = hl >> 2;
  const float arh = ar[i * 8 + head];
  float s0 = 0.f, s1 = 0.f;
  float a0 = 0.f, a1 = 0.f, a2 = 0.f, a3 = 0.f;
  float c0 = 0.f, c1 = 0.f, c2 = 0.f, c3 = 0.f;

  int e = base;
  for (; e + 8 <= end; e += 8) {
    int js[8];
    float ews[8], lgs[8];
    unsigned int hvs[8];
#pragma unroll
    for (int u = 0; u < 8; ++u) {
      uint2 ce = edge[e + u];
      js[u] = (int)ce.x;
      ews[u] = __uint_as_float(ce.y);
    }
#pragma unroll
    for (int u = 0; u < 8; ++u) lgs[u] = al[js[u] * 8 + head];
#pragma unroll
    for (int u = 0; u < 8; ++u) hvs[u] = h1f32[(size_t)js[u] * 32 + hl];
#pragma unroll
    for (int u = 0; u < 8; ++u) {
      float q = __expf(lrelu(lgs[u] + arh));
      float pw = q * ews[u];
      f32x2 lo = __builtin_amdgcn_cvt_pk_f32_fp8((int)hvs[u], false);
      f32x2 hi = __builtin_amdgcn_cvt_pk_f32_fp8((int)hvs[u], true);
      if (u & 1) {
        s1 += q;
        c0 = fmaf(pw, lo[0], c0);
        c1 = fmaf(pw, lo[1], c1);
        c2 = fmaf(pw, hi[0], c2);
        c3 = fmaf(pw, hi[1], c3);
      } else {
        s0 += q;
        a0 = fmaf(pw, lo[0], a0);
        a1 = fmaf(pw, lo[1], a1);
        a2 = fmaf(pw, hi[0], a2);
        a3 = fmaf(pw, hi[1], a3);
      }
    }
  }
  for (; e < end; ++e) {
    uint2 ce = edge[e];
    int j = (int)ce.x;
    float q = __expf(lrelu(al[j * 8 + head] + arh));
    unsigned int hv = h1f32[(size_t)j * 32 + hl];
    float pw = q * __uint_as_float(ce.y);
    f32x2 lo = __builtin_amdgcn_cvt_pk_f32_fp8((int)hv, false);
    f32x2 hi = __builtin_amdgcn_cvt_pk_f32_fp8((int)hv, true);
    s0 += q;
    a0 = fmaf(pw, lo[0], a0);
    a1 = fmaf(pw, lo[1], a1);
    a2 = fmaf(pw, hi[0], a2);
    a3 = fmaf(pw, hi[1], a3);
  }
  float inv = 1.f / (s0 + s1);
  float4 bias = *(const float4*)&b1[4 * hl];
  float o0 = elu(fmaf(a0 + c0, inv, bias.x));
  float o1 = elu(fmaf(a1 + c1, inv, bias.y));
  float o2 = elu(fmaf(a2 + c2, inv, bias.z));
  float o3 = elu(fmaf(a3 + c3, inv, bias.w));
  uint2 pk;
  pk.x = (unsigned int)f2bf(o0) | ((unsigned int)f2bf(o1) << 16);
  pk.y = (unsigned int)f2bf(o2) | ((unsigned int)f2bf(o3) << 16);
  h1eb[(size_t)i * 32 + hl] = pk;
}

// ---- GEMM2: hp2f[N][40] = fp8(h1e @ W2^T), 24 nodes/block, LDS repack ----
__global__ __launch_bounds__(256) void k_gemm2(const unsigned int* __restrict__ h1eb,
                                               const float* __restrict__ W2,
                                               unsigned int* __restrict__ hp2f32) {
  __shared__ float wl[40 * 132];
  __shared__ float hs[24 * 132];
  __shared__ unsigned int pk2[24 * 10];
  int t = threadIdx.x;
#pragma unroll
  for (int it = 0; it < 5; ++it) {
    int idx = t + 256 * it;
    int c = idx >> 5, k4 = (idx & 31) << 2;
    *(float4*)&wl[c * 132 + k4] = *(const float4*)&W2[c * 128 + k4];
  }
  int n0 = blockIdx.x * 24;
#pragma unroll
  for (int it = 0; it < 6; ++it) {
    int idx = t + 256 * it;
    int nl = idx >> 6, k = idx & 63;
    int n = n0 + nl;
    unsigned int hv = (n < NN) ? h1eb[(size_t)n * 64 + k] : 0u;
    hs[nl * 132 + 2 * k] = bflo(hv);
    hs[nl * 132 + 2 * k + 1] = bfhi(hv);
  }
  __syncthreads();
  unsigned char* pkb = (unsigned char*)pk2;
  for (int o = t; o < 960; o += 256) {
    int nl = o / 40, c = o - nl * 40;
    float a = 0.f;
#pragma unroll 8
    for (int k = 0; k < 128; k += 4) {
      float4 h = *(const float4*)&hs[nl * 132 + k];
      float4 w = *(const float4*)&wl[c * 132 + k];
      a = fmaf(h.x, w.x, a);
      a = fmaf(h.y, w.y, a);
      a = fmaf(h.z, w.z, a);
      a = fmaf(h.w, w.w, a);
    }
    pkb[nl * 40 + c] = f2fp8(a);
  }
  __syncthreads();
  if (t < 240) {
    size_t g = (size_t)n0 * 10 + t;
    if (g < (size_t)NN * 10) hp2f32[g] = pk2[t];
  }
}

// ---------------- per-node attention halves, layer 2 (fp8 table) ----------------
__global__ void k_alr2(const unsigned int* __restrict__ hp2f32, const float* __restrict__ attl,
                       const float* __restrict__ attr, float* __restrict__ al,
                       float* __restrict__ ar) {
  int n = blockIdx.x * 256 + threadIdx.x;
  if (n >= NN) return;
  const unsigned int* row = hp2f32 + (size_t)n * 10;
  float a = 0.f, b = 0.f;
#pragma unroll
  for (int c = 0; c < 10; ++c) {
    unsigned int u = row[c];
    f32x2 lo = __builtin_amdgcn_cvt_pk_f32_fp8((int)u, false);
    f32x2 hi = __builtin_amdgcn_cvt_pk_f32_fp8((int)u, true);
    a = fmaf(lo[0], attl[4 * c], a);
    a = fmaf(lo[1], attl[4 * c + 1], a);
    a = fmaf(hi[0], attl[4 * c + 2], a);
    a = fmaf(hi[1], attl[4 * c + 3], a);
    b = fmaf(lo[0], attr[4 * c], b);
    b = fmaf(lo[1], attr[4 * c + 1], b);
    b = fmaf(hi[0], attr[4 * c + 2], b);
    b = fmaf(hi[1], attr[4 * c + 3], b);
  }
  al[n] = a;
  ar[n] = b;
}

// ---- layer-2 attention prepass: edge.y <- q*ew (in place), sinv[i] = 1/sum(q) ----
__global__ __launch_bounds__(256) void k_qw2(const int* __restrict__ rs,
                                             uint2* __restrict__ edge,
                                             const float* __restrict__ al2,
                                             const float* __restrict__ ar2,
                                             float* __restrict__ sinv) {
  const int lane = threadIdx.x & 63;
  const int i = blockIdx.x * 4 + (threadIdx.x >> 6);
  if (i >= NN) return;
  const int base = rs[i], end = rs[i + 1];
  const float ari = ar2[i];
  float s = 0.f;
  for (int e = base + lane; e < end; e += 64) {
    uint2 ce = edge[e];
    float q = __expf(lrelu(al2[(int)ce.x] + ari));
    s += q;
    ((float*)&edge[e])[1] = q * __uint_as_float(ce.y);
  }
#pragma unroll
  for (int off = 1; off < 64; off <<= 1) s += __shfl_xor(s, off);
  if (lane == 0) sinv[i] = 1.f / s;
}

// ---- layer-2 aggregation + bias + log_softmax: 2 nodes/wave, 8-deep batch, fp8 gather ----
// lane hl<20 owns features 2hl, 2hl+1 (one fp8 pair = ushort)
__global__ __launch_bounds__(256) void k_agg2(const int* __restrict__ rs,
                                              const uint2* __restrict__ edge,
                                              const unsigned short* __restrict__ hp2f16,
                                              const float* __restrict__ sinv,
                                              const float* __restrict__ b2,
                                              float* __restrict__ out) {
  const int hl = threadIdx.x & 31;
  const int i = blockIdx.x * 8 + (threadIdx.x >> 5);
  if (i >= NN) return;
  const int base = rs[i], end = rs[i + 1];
  float a0 = 0.f, a1 = 0.f, c0 = 0.f, c1 = 0.f;

  int e = base;
  for (; e + 8 <= end; e += 8) {
    uint2 ce[8];
#pragma unroll
    for (int u = 0; u < 8; ++u) ce[u] = edge[e + u];
    unsigned int hv[8];
#pragma unroll
    for (int u = 0; u < 8; ++u)
      hv[u] = (hl < 20) ? (unsigned int)hp2f16[(size_t)ce[u].x * 20 + hl] : 0u;
#pragma unroll
    for (int u = 0; u < 8; ++u) {
      float p = __uint_as_float(ce[u].y);
      f32x2 v = __builtin_amdgcn_cvt_pk_f32_fp8((int)hv[u], false);
      if (u & 1) {
        c0 = fmaf(p, v[0], c0);
        c1 = fmaf(p, v[1], c1);
      } else {
        a0 = fmaf(p, v[0], a0);
        a1 = fmaf(p, v[1], a1);
      }
    }
  }
  for (; e < end; ++e) {
    uint2 ce = edge[e];
    unsigned int hv = (hl < 20) ? (unsigned int)hp2f16[(size_t)ce.x * 20 + hl] : 0u;
    float p = __uint_as_float(ce.y);
    f32x2 v = __builtin_amdgcn_cvt_pk_f32_fp8((int)hv, false);
    a0 = fmaf(p, v[0], a0);
    a1 = fmaf(p, v[1], a1);
  }
  a0 += c0;
  a1 += c1;
  float inv = sinv[i];
  float v0 = -1e30f, v1 = -1e30f;
  if (hl < 20) {
    v0 = fmaf(a0, inv, b2[2 * hl]);
    v1 = fmaf(a1, inv, b2[2 * hl + 1]);
  }
  float mx = fmaxf(v0, v1);
#pragma unroll
  for (int off = 1; off < 32; off <<= 1) mx = fmaxf(mx, __shfl_xor(mx, off, 32));
  float se = (hl < 20) ? __expf(v0 - mx) + __expf(v1 - mx) : 0.f;
#pragma unroll
  for (int off = 1; off < 32; off <<= 1) se += __shfl_xor(se, off, 32);
  if (hl < 20) {
    float ls = mx + __logf(se);
    ((float2*)(out + (size_t)i * 40))[hl] = make_float2(v0 - ls, v1 - ls);
  }
}

extern "C" void kernel_launch(void* const* d_in, const int* in_sizes, int n_in,
                              void* d_out, int out_size, void* d_ws, size_t ws_size,
                              hipStream_t stream) {
  const float* x     = (const float*)d_in[0];
  const int*   esrc  = (const int*)d_in[1];
  const int*   edst  = (const int*)d_in[2];
  const float* ew    = (const float*)d_in[3];
  const float* W1    = (const float*)d_in[4];
  const float* attl1 = (const float*)d_in[5];
  const float* attr1 = (const float*)d_in[6];
  const float* b1    = (const float*)d_in[7];
  const float* W2    = (const float*)d_in[8];
  const float* attl2 = (const float*)d_in[9];
  const float* attr2 = (const float*)d_in[10];
  const float* b2    = (const float*)d_in[11];
  float* out = (float*)d_out;

  char* w = (char*)d_ws;
  auto take = [&](size_t bytes) {
    char* p = w;
    w += (bytes + 255) & ~(size_t)255;
    return p;
  };
  unsigned int* h1f  = (unsigned int*)take((size_t)NN * F1);       // fp8 table, 6.4 MB
  unsigned int* h1eb = (unsigned int*)take((size_t)NN * 64 * 4);   // bf16, 12.8 MB
  float* al1 = (float*)take((size_t)NN * NH * 4);
  float* ar1 = (float*)take((size_t)NN * NH * 4);
  unsigned int* hp2f = (unsigned int*)take((size_t)NN * 40);       // fp8 table, 2 MB
  float* al2 = (float*)take((size_t)NN * 4);
  float* ar2 = (float*)take((size_t)NN * 4);
  float* sinv = (float*)take((size_t)NN * 4);
  int*   rs  = (int*)take((size_t)(NN + 1) * 4);
  uint2* edge = (uint2*)take((size_t)NT * 8);
  unsigned short* W1b = (unsigned short*)take((size_t)F1 * NF * 2); // 128 KB bf16 W1
  int* bktCnt = (int*)take(NB * 4);
  int* bbase  = (int*)take(NB * 4);

  // staging aliases h1f+h1eb (20 MB contiguous; CSR build precedes their writers)
  uint2* bSrcEw = (uint2*)h1f;                                           // 16.06 MB
  unsigned short* bDst = (unsigned short*)((char*)h1f + (size_t)NB * BCAP * 8);  // 4.01 MB

  // CSR build (by destination), self loop = slot 0 of each segment
  hipMemsetAsync(bktCnt, 0, NB * 4, stream);
  k_binA<<<(NE + TILE - 1) / TILE, 256, 0, stream>>>(esrc, edst, ew, bktCnt, bSrcEw, bDst);
  k_bscan<<<1, 256, 0, stream>>>(bktCnt, bbase, rs);
  k_fillB<<<NB, 256, 0, stream>>>(bktCnt, bbase, bSrcEw, bDst, ew, rs, edge);

  // layer 1
  k_w1bf<<<64, 256, 0, stream>>>(W1, W1b);
  k_gemm1<<<(NN + 31) / 32, 256, 0, stream>>>(x, W1b, attl1, attr1, h1f, al1, ar1);
  k_agg1<<<(NN + 7) / 8, 256, 0, stream>>>(rs, edge, h1f, al1, ar1, b1, (uint2*)h1eb);

  // layer 2
  k_gemm2<<<(NN + 23) / 24, 256, 0, stream>>>(h1eb, W2, hp2f);
  k_alr2<<<(NN + 255) / 256, 256, 0, stream>>>(hp2f, attl2, attr2, al2, ar2);
  k_qw2<<<(NN + 3) / 4, 256, 0, stream>>>(rs, edge, al2, ar2, sinv);
  k_agg2<<<(NN + 3) / 8, 256, 0, stream>>>(rs, edge, (const unsigned short*)hp2f, sinv, b2, out);
}

// Round 10
// 190.150 us; speedup vs baseline: 1.8044x; 1.1127x over previous
//
#include <hip/hip_runtime.h>

#define NN 50000
#define NE 1600000
#define NT (NE + NN)   // total edges incl self loops
#define NF 512
#define F1 128
#define NH 8
#define F2 40

#define NB 196         // dst buckets of 256 nodes
#define BCAP 10240     // per-bucket staging capacity (mean 8163, sd ~90)
#define TILE 4096

typedef __attribute__((ext_vector_type(8))) short short8;
typedef __attribute__((ext_vector_type(4))) short short4v;
typedef __attribute__((ext_vector_type(4))) float f32x4;
typedef __attribute__((ext_vector_type(2))) float f32x2;

__device__ __forceinline__ float lrelu(float x) { return fmaxf(x, 0.2f * x); }

__device__ __forceinline__ unsigned short f2bf(float f) {
  unsigned int u = __float_as_uint(f);
  u += 0x7fffu + ((u >> 16) & 1u);  // RNE
  return (unsigned short)(u >> 16);
}
__device__ __forceinline__ float bfhi(unsigned int dw) { return __uint_as_float(dw & 0xffff0000u); }
__device__ __forceinline__ float bflo(unsigned int dw) { return __uint_as_float(dw << 16); }
__device__ __forceinline__ float elu(float x) { return x > 0.f ? x : __expf(x) - 1.f; }

__device__ __forceinline__ unsigned char f2fp8(float v) {
  return (unsigned char)(__builtin_amdgcn_cvt_pk_fp8_f32(v, v, 0, false) & 0xFF);
}

// ---------------- CSR build phase A: bucket-bin edges with LDS tile sort ----------------
__global__ __launch_bounds__(256) void k_binA(const int* __restrict__ esrc,
                                              const int* __restrict__ edst,
                                              const float* __restrict__ ew,
                                              int* __restrict__ bktCnt,
                                              uint2* __restrict__ bSrcEw,
                                              unsigned short* __restrict__ bDst) {
  __shared__ int cnt[NB];
  __shared__ int scn[NB];
  __shared__ int gbase[NB];
  __shared__ int cur[NB];
  __shared__ int tmp[256];
  __shared__ uint2 stSE[TILE];
  __shared__ unsigned short stD[TILE];
  const int t = threadIdx.x;
  const int e0 = blockIdx.x * TILE;

  for (int b = t; b < NB; b += 256) cnt[b] = 0;
  __syncthreads();

  unsigned int sd[16];
  float wv[16];
#pragma unroll
  for (int u = 0; u < 16; ++u) {
    int e = e0 + t + 256 * u;
    if (e < NE) {
      unsigned int s = (unsigned int)esrc[e];
      unsigned int d = (unsigned int)edst[e];
      sd[u] = s | (d << 16);
      wv[u] = ew[e];
      atomicAdd(&cnt[d >> 8], 1);
    } else {
      sd[u] = 0xFFFFFFFFu;
    }
  }
  __syncthreads();

  int v = (t < NB) ? cnt[t] : 0;
  tmp[t] = v;
  __syncthreads();
  for (int off = 1; off < 256; off <<= 1) {
    int a = (t >= off) ? tmp[t - off] : 0;
    __syncthreads();
    tmp[t] += a;
    __syncthreads();
  }
  if (t < NB) {
    scn[t] = tmp[t] - v;
    cur[t] = tmp[t] - v;
    gbase[t] = atomicAdd(&bktCnt[t], v);
  }
  __syncthreads();

#pragma unroll
  for (int u = 0; u < 16; ++u) {
    if (sd[u] != 0xFFFFFFFFu) {
      unsigned int d = sd[u] >> 16;
      int p = atomicAdd(&cur[d >> 8], 1);
      stSE[p] = make_uint2(sd[u] & 0xFFFFu, __float_as_uint(wv[u]));
      stD[p] = (unsigned short)d;
    }
  }
  __syncthreads();

  int tot = NE - e0;
  if (tot > TILE) tot = TILE;
  for (int k = t; k < tot; k += 256) {
    int d = stD[k];
    int b = d >> 8;
    int idx = gbase[b] + (k - scn[b]);
    bSrcEw[(size_t)b * BCAP + idx] = stSE[k];
    bDst[(size_t)b * BCAP + idx] = (unsigned short)d;
  }
}

// ---------------- CSR build: scan bucket totals (incl self loops) ----------------
__global__ void k_bscan(const int* __restrict__ bktCnt, int* __restrict__ base,
                        int* __restrict__ rs) {
  __shared__ int tmp[256];
  int t = threadIdx.x;
  int nInB = 0;
  if (t < NB) nInB = (t == NB - 1) ? (NN - (NB - 1) * 256) : 256;
  int v = (t < NB) ? bktCnt[t] + nInB : 0;
  tmp[t] = v;
  __syncthreads();
  for (int off = 1; off < 256; off <<= 1) {
    int a = (t >= off) ? tmp[t - off] : 0;
    __syncthreads();
    tmp[t] += a;
    __syncthreads();
  }
  if (t < NB) base[t] = tmp[t] - v;
  if (t == 0) rs[NN] = NT;
}

// ---------------- CSR build phase B: per-bucket local hist/scan/scatter ----------------
__global__ __launch_bounds__(256) void k_fillB(const int* __restrict__ bktCnt,
                                               const int* __restrict__ base,
                                               const uint2* __restrict__ bSrcEw,
                                               const unsigned short* __restrict__ bDst,
                                               const float* __restrict__ ew,
                                               int* __restrict__ rs,
                                               uint2* __restrict__ edge) {
  __shared__ int cnt[256], cur[256], tmp[256];
  const int b = blockIdx.x, t = threadIdx.x;
  const int n0 = b * 256;
  const int nNodes = (n0 + 256 <= NN) ? 256 : (NN - n0);
  const int cE = bktCnt[b];
  const int gb = base[b];

  cnt[t] = 0;
  __syncthreads();
  for (int k = t; k < cE; k += 256) atomicAdd(&cnt[bDst[(size_t)b * BCAP + k] & 255], 1);
  __syncthreads();

  int v = (t < nNodes) ? cnt[t] + 1 : 0;  // +1 self loop
  tmp[t] = v;
  __syncthreads();
  for (int off = 1; off < 256; off <<= 1) {
    int a = (t >= off) ? tmp[t - off] : 0;
    __syncthreads();
    tmp[t] += a;
    __syncthreads();
  }
  int off_ = tmp[t] - v;  // exclusive
  if (t < nNodes) {
    rs[n0 + t] = gb + off_;
    cur[t] = off_ + 1;  // slot 0 = self loop
    edge[(size_t)gb + off_] = make_uint2((unsigned int)(n0 + t), __float_as_uint(ew[NE + n0 + t]));
  }
  __syncthreads();

  for (int k = t; k < cE; k += 256) {
    uint2 se = bSrcEw[(size_t)b * BCAP + k];
    int d = bDst[(size_t)b * BCAP + k] & 255;
    int p = atomicAdd(&cur[d], 1);
    edge[(size_t)gb + p] = se;
  }
}

// ------- weight prepass: W1 (128x512) and W2 (40x128, pad to 48 rows) -> bf16 -------
__global__ void k_wprep(const float* __restrict__ W1, const float* __restrict__ W2,
                        unsigned short* __restrict__ W1b, unsigned short* __restrict__ W2b) {
  int i = blockIdx.x * 256 + threadIdx.x;
  if (i < 16384) {  // W1: 16384 float4s
    float4 v = ((const float4*)W1)[i];
    short4v b;
    b[0] = (short)f2bf(v.x); b[1] = (short)f2bf(v.y);
    b[2] = (short)f2bf(v.z); b[3] = (short)f2bf(v.w);
    *(short4v*)&W1b[(size_t)i * 4] = b;
  } else if (i < 16384 + 1536) {  // W2b: 48 rows x 32 float4s
    int j = i - 16384;
    int col = j >> 5, q = j & 31;
    short4v b = {0, 0, 0, 0};
    if (col < 40) {
      float4 v = ((const float4*)W2)[col * 32 + q];
      b[0] = (short)f2bf(v.x); b[1] = (short)f2bf(v.y);
      b[2] = (short)f2bf(v.z); b[3] = (short)f2bf(v.w);
    }
    *(short4v*)&W2b[(size_t)col * 128 + q * 4] = b;
  }
}

// ---- GEMM1 (MFMA bf16): h1f[N][128] = fp8(x @ W1^T); BM=32, BK=64; fused alr1 ----
__global__ __launch_bounds__(256) void k_gemm1(const float* __restrict__ x,
                                               const unsigned short* __restrict__ W1b,
                                               const float* __restrict__ attl,
                                               const float* __restrict__ attr,
                                               unsigned int* __restrict__ h1f32,
                                               float* __restrict__ al,
                                               float* __restrict__ ar) {
  __shared__ unsigned short As[32 * 72];    // 4.6 KB
  __shared__ unsigned short Bs[128 * 72];   // 18.4 KB
  __shared__ unsigned int pk32[32 * 32];    // 4 KB fp8 repack
  const int t = threadIdx.x;
  const int w = t >> 6, lane = t & 63;
  const int g16 = lane >> 4, r16 = lane & 15;
  const int m0 = blockIdx.x * 32;
  const int r0 = (w & 1) * 16;   // wave rows
  const int c0 = (w >> 1) * 64;  // wave cols

  f32x4 acc[4];
#pragma unroll
  for (int b = 0; b < 4; ++b) acc[b] = (f32x4){0.f, 0.f, 0.f, 0.f};

  for (int kc = 0; kc < NF; kc += 64) {
    __syncthreads();
#pragma unroll
    for (int i = 0; i < 2; ++i) {
      int idx = t + 256 * i;      // 0..511
      int row = idx >> 4;         // 0..31
      int k4 = (idx & 15) << 2;   // 0..60
      int n = m0 + row;
      float4 v = make_float4(0.f, 0.f, 0.f, 0.f);
      if (n < NN) v = *(const float4*)&x[(size_t)n * NF + kc + k4];
      short4v b;
      b[0] = (short)f2bf(v.x); b[1] = (short)f2bf(v.y);
      b[2] = (short)f2bf(v.z); b[3] = (short)f2bf(v.w);
      *(short4v*)&As[row * 72 + k4] = b;
    }
#pragma unroll
    for (int i = 0; i < 4; ++i) {
      int idx = t + 256 * i;      // 0..1023
      int col = idx >> 3;         // 0..127
      int k8 = (idx & 7) << 3;    // 0..56
      *(short8*)&Bs[col * 72 + k8] = *(const short8*)&W1b[(size_t)col * NF + kc + k8];
    }
    __syncthreads();

    short8 afr[2], bfr[4][2];
#pragma unroll
    for (int ks = 0; ks < 2; ++ks)
      afr[ks] = *(const short8*)&As[(r0 + r16) * 72 + ks * 32 + g16 * 8];
#pragma unroll
    for (int nj = 0; nj < 4; ++nj)
#pragma unroll
      for (int ks = 0; ks < 2; ++ks)
        bfr[nj][ks] = *(const short8*)&Bs[(c0 + nj * 16 + r16) * 72 + ks * 32 + g16 * 8];
#pragma unroll
    for (int nj = 0; nj < 4; ++nj)
#pragma unroll
      for (int ks = 0; ks < 2; ++ks)
        acc[nj] = __builtin_amdgcn_mfma_f32_16x16x32_bf16(afr[ks], bfr[nj][ks], acc[nj], 0, 0, 0);
  }

  // fp8-pack into LDS
  unsigned char* pkb = (unsigned char*)pk32;
  __syncthreads();
#pragma unroll
  for (int nj = 0; nj < 4; ++nj)
#pragma unroll
    for (int r = 0; r < 4; ++r)
      pkb[(r0 + g16 * 4 + r) * 128 + c0 + nj * 16 + r16] = f2fp8(acc[nj][r]);
  __syncthreads();

  // coalesced store: 32 rows x 8 uint4 = 256 threads
  {
    int row = t >> 3, q = t & 7;
    int n = m0 + row;
    if (n < NN) ((uint4*)h1f32)[(size_t)n * 8 + q] = ((const uint4*)pk32)[row * 8 + q];
  }
  // fused alr1: thread -> (row=t>>3, head=t&7)
  {
    int row = t >> 3, h = t & 7;
    int n = m0 + row;
    if (n < NN) {
      float a = 0.f, b = 0.f;
#pragma unroll
      for (int c = 0; c < 4; ++c) {
        unsigned int u = pk32[row * 32 + h * 4 + c];
        f32x2 lo = __builtin_amdgcn_cvt_pk_f32_fp8((int)u, false);
        f32x2 hi = __builtin_amdgcn_cvt_pk_f32_fp8((int)u, true);
        int f0 = h * 16 + 4 * c;
        a = fmaf(lo[0], attl[f0], a);
        a = fmaf(lo[1], attl[f0 + 1], a);
        a = fmaf(hi[0], attl[f0 + 2], a);
        a = fmaf(hi[1], attl[f0 + 3], a);
        b = fmaf(lo[0], attr[f0], b);
        b = fmaf(lo[1], attr[f0 + 1], b);
        b = fmaf(hi[0], attr[f0 + 2], b);
        b = fmaf(hi[1], attr[f0 + 3], b);
      }
      al[n * 8 + h] = a;
      ar[n * 8 + h] = b;
    }
  }
}

// ---- layer-1 aggregation: 2 nodes/wave (32-lane halves), plain exp, fp8 gather ----
__global__ __launch_bounds__(256) void k_agg1(const int* __restrict__ rs,
                                              const uint2* __restrict__ edge,
                                              const unsigned int* __restrict__ h1f32,
                                              const float* __restrict__ al,
                                              const float* __restrict__ ar,
                                              const float* __restrict__ b1,
                                              uint2* __restrict__ h1eb) {
  const int hl = threadIdx.x & 31;
  const int i = blockIdx.x * 8 + (threadIdx.x >> 5);
  if (i >= NN) return;
  const int base = rs[i], end = rs[i + 1];
  const int head = hl >> 2;
  const float arh = ar[i * 8 + head];
  float s0 = 0.f, s1 = 0.f;
  float a0 = 0.f, a1 = 0.f, a2 = 0.f, a3 = 0.f;
  float c0 = 0.f, c1 = 0.f, c2 = 0.f, c3 = 0.f;

  int e = base;
  for (; e + 8 <= end; e += 8) {
    int js[8];
    float ews[8], lgs[8];
    unsigned int hvs[8];
#pragma unroll
    for (int u = 0; u < 8; ++u) {
      uint2 ce = edge[e + u];
      js[u] = (int)ce.x;
      ews[u] = __uint_as_float(ce.y);
    }
#pragma unroll
    for (int u = 0; u < 8; ++u) lgs[u] = al[js[u] * 8 + head];
#pragma unroll
    for (int u = 0; u < 8; ++u) hvs[u] = h1f32[(size_t)js[u] * 32 + hl];
#pragma unroll
    for (int u = 0; u < 8; ++u) {
      float q = __expf(lrelu(lgs[u] + arh));
      float pw = q * ews[u];
      f32x2 lo = __builtin_amdgcn_cvt_pk_f32_fp8((int)hvs[u], false);
      f32x2 hi = __builtin_amdgcn_cvt_pk_f32_fp8((int)hvs[u], true);
      if (u & 1) {
        s1 += q;
        c0 = fmaf(pw, lo[0], c0);
        c1 = fmaf(pw, lo[1], c1);
        c2 = fmaf(pw, hi[0], c2);
        c3 = fmaf(pw, hi[1], c3);
      } else {
        s0 += q;
        a0 = fmaf(pw, lo[0], a0);
        a1 = fmaf(pw, lo[1], a1);
        a2 = fmaf(pw, hi[0], a2);
        a3 = fmaf(pw, hi[1], a3);
      }
    }
  }
  for (; e < end; ++e) {
    uint2 ce = edge[e];
    int j = (int)ce.x;
    float q = __expf(lrelu(al[j * 8 + head] + arh));
    unsigned int hv = h1f32[(size_t)j * 32 + hl];
    float pw = q * __uint_as_float(ce.y);
    f32x2 lo = __builtin_amdgcn_cvt_pk_f32_fp8((int)hv, false);
    f32x2 hi = __builtin_amdgcn_cvt_pk_f32_fp8((int)hv, true);
    s0 += q;
    a0 = fmaf(pw, lo[0], a0);
    a1 = fmaf(pw, lo[1], a1);
    a2 = fmaf(pw, hi[0], a2);
    a3 = fmaf(pw, hi[1], a3);
  }
  float inv = 1.f / (s0 + s1);
  float4 bias = *(const float4*)&b1[4 * hl];
  float o0 = elu(fmaf(a0 + c0, inv, bias.x));
  float o1 = elu(fmaf(a1 + c1, inv, bias.y));
  float o2 = elu(fmaf(a2 + c2, inv, bias.z));
  float o3 = elu(fmaf(a3 + c3, inv, bias.w));
  uint2 pk;
  pk.x = (unsigned int)f2bf(o0) | ((unsigned int)f2bf(o1) << 16);
  pk.y = (unsigned int)f2bf(o2) | ((unsigned int)f2bf(o3) << 16);
  h1eb[(size_t)i * 32 + hl] = pk;
}

// ---- GEMM2 (MFMA bf16, one K-shot): hp2f[N][40] = fp8(h1e @ W2^T); fused alr2 ----
// BM=64 rows, N=48 (40 valid), K=128 staged once. 4 waves: wave w owns rows w*16..w*16+15.
__global__ __launch_bounds__(256) void k_gemm2(const uint4* __restrict__ h1eb4,
                                               const unsigned short* __restrict__ W2b,
                                               const float* __restrict__ attl,
                                               const float* __restrict__ attr,
                                               unsigned int* __restrict__ hp2f32,
                                               float* __restrict__ al,
                                               float* __restrict__ ar) {
  __shared__ unsigned short As[64 * 136];   // 17.4 KB
  __shared__ unsigned short Bs[48 * 136];   // 13.1 KB
  __shared__ unsigned int pkd[64 * 10];     // 2.5 KB fp8 repack
  const int t = threadIdx.x;
  const int w = t >> 6, lane = t & 63;
  const int g16 = lane >> 4, r16 = lane & 15;
  const int n0 = blockIdx.x * 64;

  // stage A: 64 rows x 16 uint4 (= 128 bf16/row)
#pragma unroll
  for (int i = 0; i < 4; ++i) {
    int idx = t + 256 * i;       // 0..1023
    int row = idx >> 4, q = idx & 15;
    int n = n0 + row;
    uint4 v = make_uint4(0u, 0u, 0u, 0u);
    if (n < NN) v = h1eb4[(size_t)n * 16 + q];
    *(uint4*)&As[row * 136 + q * 8] = v;
  }
  // stage B: 48 cols x 16 uint4
#pragma unroll
  for (int i = 0; i < 3; ++i) {
    int idx = t + 256 * i;       // 0..767
    int col = idx >> 4, q = idx & 15;
    *(uint4*)&Bs[col * 136 + q * 8] = ((const uint4*)W2b)[col * 16 + q];
  }
  __syncthreads();

  f32x4 acc[3];
#pragma unroll
  for (int b = 0; b < 3; ++b) acc[b] = (f32x4){0.f, 0.f, 0.f, 0.f};
  short8 afr[4];
#pragma unroll
  for (int kc = 0; kc < 4; ++kc)
    afr[kc] = *(const short8*)&As[(w * 16 + r16) * 136 + kc * 32 + g16 * 8];
#pragma unroll
  for (int nt = 0; nt < 3; ++nt) {
#pragma unroll
    for (int kc = 0; kc < 4; ++kc) {
      short8 bfr = *(const short8*)&Bs[(nt * 16 + r16) * 136 + kc * 32 + g16 * 8];
      acc[nt] = __builtin_amdgcn_mfma_f32_16x16x32_bf16(afr[kc], bfr, acc[nt], 0, 0, 0);
    }
  }

  // fp8-pack into LDS: row = w*16 + g16*4 + r, col = nt*16 + r16 (keep col<40)
  unsigned char* pkb = (unsigned char*)pkd;
  __syncthreads();
#pragma unroll
  for (int nt = 0; nt < 3; ++nt) {
    int col = nt * 16 + r16;
    if (col < 40) {
#pragma unroll
      for (int r = 0; r < 4; ++r)
        pkb[(w * 16 + g16 * 4 + r) * 40 + col] = f2fp8(acc[nt][r]);
    }
  }
  __syncthreads();

  // coalesced store: 64 rows x 10 dwords
  for (int idx = t; idx < 640; idx += 256) {
    int row = idx / 10, q = idx - row * 10;
    int n = n0 + row;
    if (n < NN) hp2f32[(size_t)n * 10 + q] = pkd[row * 10 + q];
  }
  // fused alr2: one thread per row
  if (t < 64) {
    int n = n0 + t;
    if (n < NN) {
      float a = 0.f, b = 0.f;
#pragma unroll
      for (int c = 0; c < 10; ++c) {
        unsigned int u = pkd[t * 10 + c];
        f32x2 lo = __builtin_amdgcn_cvt_pk_f32_fp8((int)u, false);
        f32x2 hi = __builtin_amdgcn_cvt_pk_f32_fp8((int)u, true);
        a = fmaf(lo[0], attl[4 * c], a);
        a = fmaf(lo[1], attl[4 * c + 1], a);
        a = fmaf(hi[0], attl[4 * c + 2], a);
        a = fmaf(hi[1], attl[4 * c + 3], a);
        b = fmaf(lo[0], attr[4 * c], b);
        b = fmaf(lo[1], attr[4 * c + 1], b);
        b = fmaf(hi[0], attr[4 * c + 2], b);
        b = fmaf(hi[1], attr[4 * c + 3], b);
      }
      al[n] = a;
      ar[n] = b;
    }
  }
}

// ---- layer-2 attention prepass: edge.y <- q*ew (in place), sinv[i] = 1/sum(q) ----
__global__ __launch_bounds__(256) void k_qw2(const int* __restrict__ rs,
                                             uint2* __restrict__ edge,
                                             const float* __restrict__ al2,
                                             const float* __restrict__ ar2,
                                             float* __restrict__ sinv) {
  const int lane = threadIdx.x & 63;
  const int i = blockIdx.x * 4 + (threadIdx.x >> 6);
  if (i >= NN) return;
  const int base = rs[i], end = rs[i + 1];
  const float ari = ar2[i];
  float s = 0.f;
  for (int e = base + lane; e < end; e += 64) {
    uint2 ce = edge[e];
    float q = __expf(lrelu(al2[(int)ce.x] + ari));
    s += q;
    ((float*)&edge[e])[1] = q * __uint_as_float(ce.y);
  }
#pragma unroll
  for (int off = 1; off < 64; off <<= 1) s += __shfl_xor(s, off);
  if (lane == 0) sinv[i] = 1.f / s;
}

// ---- layer-2 aggregation + bias + log_softmax: 2 nodes/wave, 8-deep batch, fp8 gather ----
// lane hl<20 owns features 2hl, 2hl+1 (one fp8 pair = ushort)
__global__ __launch_bounds__(256) void k_agg2(const int* __restrict__ rs,
                                              const uint2* __restrict__ edge,
                                              const unsigned short* __restrict__ hp2f16,
                                              const float* __restrict__ sinv,
                                              const float* __restrict__ b2,
                                              float* __restrict__ out) {
  const int hl = threadIdx.x & 31;
  const int i = blockIdx.x * 8 + (threadIdx.x >> 5);
  if (i >= NN) return;
  const int base = rs[i], end = rs[i + 1];
  float a0 = 0.f, a1 = 0.f, c0 = 0.f, c1 = 0.f;

  int e = base;
  for (; e + 8 <= end; e += 8) {
    uint2 ce[8];
#pragma unroll
    for (int u = 0; u < 8; ++u) ce[u] = edge[e + u];
    unsigned int hv[8];
#pragma unroll
    for (int u = 0; u < 8; ++u)
      hv[u] = (hl < 20) ? (unsigned int)hp2f16[(size_t)ce[u].x * 20 + hl] : 0u;
#pragma unroll
    for (int u = 0; u < 8; ++u) {
      float p = __uint_as_float(ce[u].y);
      f32x2 v = __builtin_amdgcn_cvt_pk_f32_fp8((int)hv[u], false);
      if (u & 1) {
        c0 = fmaf(p, v[0], c0);
        c1 = fmaf(p, v[1], c1);
      } else {
        a0 = fmaf(p, v[0], a0);
        a1 = fmaf(p, v[1], a1);
      }
    }
  }
  for (; e < end; ++e) {
    uint2 ce = edge[e];
    unsigned int hv = (hl < 20) ? (unsigned int)hp2f16[(size_t)ce.x * 20 + hl] : 0u;
    float p = __uint_as_float(ce.y);
    f32x2 v = __builtin_amdgcn_cvt_pk_f32_fp8((int)hv, false);
    a0 = fmaf(p, v[0], a0);
    a1 = fmaf(p, v[1], a1);
  }
  a0 += c0;
  a1 += c1;
  float inv = sinv[i];
  float v0 = -1e30f, v1 = -1e30f;
  if (hl < 20) {
    v0 = fmaf(a0, inv, b2[2 * hl]);
    v1 = fmaf(a1, inv, b2[2 * hl + 1]);
  }
  float mx = fmaxf(v0, v1);
#pragma unroll
  for (int off = 1; off < 32; off <<= 1) mx = fmaxf(mx, __shfl_xor(mx, off, 32));
  float se = (hl < 20) ? __expf(v0 - mx) + __expf(v1 - mx) : 0.f;
#pragma unroll
  for (int off = 1; off < 32; off <<= 1) se += __shfl_xor(se, off, 32);
  if (hl < 20) {
    float ls = mx + __logf(se);
    ((float2*)(out + (size_t)i * 40))[hl] = make_float2(v0 - ls, v1 - ls);
  }
}

extern "C" void kernel_launch(void* const* d_in, const int* in_sizes, int n_in,
                              void* d_out, int out_size, void* d_ws, size_t ws_size,
                              hipStream_t stream) {
  const float* x     = (const float*)d_in[0];
  const int*   esrc  = (const int*)d_in[1];
  const int*   edst  = (const int*)d_in[2];
  const float* ew    = (const float*)d_in[3];
  const float* W1    = (const float*)d_in[4];
  const float* attl1 = (const float*)d_in[5];
  const float* attr1 = (const float*)d_in[6];
  const float* b1    = (const float*)d_in[7];
  const float* W2    = (const float*)d_in[8];
  const float* attl2 = (const float*)d_in[9];
  const float* attr2 = (const float*)d_in[10];
  const float* b2    = (const float*)d_in[11];
  float* out = (float*)d_out;

  char* w = (char*)d_ws;
  auto take = [&](size_t bytes) {
    char* p = w;
    w += (bytes + 255) & ~(size_t)255;
    return p;
  };
  unsigned int* h1f  = (unsigned int*)take((size_t)NN * F1);       // fp8 table, 6.4 MB
  unsigned int* h1eb = (unsigned int*)take((size_t)NN * 64 * 4);   // bf16, 12.8 MB
  float* al1 = (float*)take((size_t)NN * NH * 4);
  float* ar1 = (float*)take((size_t)NN * NH * 4);
  unsigned int* hp2f = (unsigned int*)take((size_t)NN * 40);       // fp8 table, 2 MB
  float* al2 = (float*)take((size_t)NN * 4);
  float* ar2 = (float*)take((size_t)NN * 4);
  float* sinv = (float*)take((size_t)NN * 4);
  int*   rs  = (int*)take((size_t)(NN + 1) * 4);
  uint2* edge = (uint2*)take((size_t)NT * 8);
  unsigned short* W1b = (unsigned short*)take((size_t)F1 * NF * 2); // 128 KB bf16 W1
  unsigned short* W2b = (unsigned short*)take((size_t)48 * 128 * 2); // 12 KB bf16 W2 (pad 48)
  int* bktCnt = (int*)take(NB * 4);
  int* bbase  = (int*)take(NB * 4);

  // staging aliases h1f+h1eb (20 MB contiguous; CSR build precedes their writers)
  uint2* bSrcEw = (uint2*)h1f;                                           // 16.06 MB
  unsigned short* bDst = (unsigned short*)((char*)h1f + (size_t)NB * BCAP * 8);  // 4.01 MB

  // CSR build (by destination), self loop = slot 0 of each segment
  hipMemsetAsync(bktCnt, 0, NB * 4, stream);
  k_binA<<<(NE + TILE - 1) / TILE, 256, 0, stream>>>(esrc, edst, ew, bktCnt, bSrcEw, bDst);
  k_bscan<<<1, 256, 0, stream>>>(bktCnt, bbase, rs);
  k_fillB<<<NB, 256, 0, stream>>>(bktCnt, bbase, bSrcEw, bDst, ew, rs, edge);

  // layer 1
  k_wprep<<<70, 256, 0, stream>>>(W1, W2, W1b, W2b);
  k_gemm1<<<(NN + 31) / 32, 256, 0, stream>>>(x, W1b, attl1, attr1, h1f, al1, ar1);
  k_agg1<<<(NN + 7) / 8, 256, 0, stream>>>(rs, edge, h1f, al1, ar1, b1, (uint2*)h1eb);

  // layer 2
  k_gemm2<<<(NN + 63) / 64, 256, 0, stream>>>((const uint4*)h1eb, W2b, attl2, attr2,
                                              hp2f, al2, ar2);
  k_qw2<<<(NN + 3) / 4, 256, 0, stream>>>(rs, edge, al2, ar2, sinv);
  k_agg2<<<(NN + 3) / 8, 256, 0, stream>>>(rs, edge, (const unsigned short*)hp2f, sinv, b2, out);
}

// Round 12
// 166.165 us; speedup vs baseline: 2.0649x; 1.1443x over previous
//
#include <hip/hip_runtime.h>

#define NN 50000
#define NE 1600000
#define NT (NE + NN)   // total edges incl self loops
#define NF 512
#define F1 128
#define NH 8
#define F2 40

#define NB 196         // dst buckets of 256 nodes
#define BCAP 10240     // per-bucket staging capacity (mean 8163, sd ~90)
#define TILE 4096

#define NB_PREP 70     // wprep blocks in k_prep
#define NB_BINA ((NE + TILE - 1) / TILE)   // 391
#define NB_G1 ((NN + 31) / 32)             // 1563

typedef __attribute__((ext_vector_type(8))) short short8;
typedef __attribute__((ext_vector_type(4))) short short4v;
typedef __attribute__((ext_vector_type(4))) float f32x4;
typedef __attribute__((ext_vector_type(2))) float f32x2;

__device__ __forceinline__ float lrelu(float x) { return fmaxf(x, 0.2f * x); }

__device__ __forceinline__ unsigned short f2bf(float f) {
  unsigned int u = __float_as_uint(f);
  u += 0x7fffu + ((u >> 16) & 1u);  // RNE
  return (unsigned short)(u >> 16);
}
__device__ __forceinline__ float bfhi(unsigned int dw) { return __uint_as_float(dw & 0xffff0000u); }
__device__ __forceinline__ float bflo(unsigned int dw) { return __uint_as_float(dw << 16); }
__device__ __forceinline__ float elu(float x) { return x > 0.f ? x : __expf(x) - 1.f; }

__device__ __forceinline__ unsigned char f2fp8(float v) {
  return (unsigned char)(__builtin_amdgcn_cvt_pk_fp8_f32(v, v, 0, false) & 0xFF);
}

// ================= k_prep: wprep (blocks 0..69) || binA (blocks 70..460) =================
__global__ __launch_bounds__(256) void k_prep(const float* __restrict__ W1,
                                              const float* __restrict__ W2,
                                              unsigned short* __restrict__ W1b,
                                              unsigned short* __restrict__ W2b,
                                              const int* __restrict__ esrc,
                                              const int* __restrict__ edst,
                                              const float* __restrict__ ew,
                                              int* __restrict__ bktCnt,
                                              uint2* __restrict__ bSrcEw,
                                              unsigned short* __restrict__ bDst) {
  __shared__ __align__(16) char sm[46080];
  const int t = threadIdx.x;

  if (blockIdx.x < NB_PREP) {
    // ---- weight prepass ----
    int i = blockIdx.x * 256 + t;
    if (i < 16384) {  // W1: 16384 float4s
      float4 v = ((const float4*)W1)[i];
      short4v b;
      b[0] = (short)f2bf(v.x); b[1] = (short)f2bf(v.y);
      b[2] = (short)f2bf(v.z); b[3] = (short)f2bf(v.w);
      *(short4v*)&W1b[(size_t)i * 4] = b;
    } else if (i < 16384 + 1536) {  // W2b: 48 rows x 32 float4s (pad rows 40..47 with 0)
      int j = i - 16384;
      int col = j >> 5, q = j & 31;
      short4v b = {0, 0, 0, 0};
      if (col < 40) {
        float4 v = ((const float4*)W2)[col * 32 + q];
        b[0] = (short)f2bf(v.x); b[1] = (short)f2bf(v.y);
        b[2] = (short)f2bf(v.z); b[3] = (short)f2bf(v.w);
      }
      *(short4v*)&W2b[(size_t)col * 128 + q * 4] = b;
    }
    return;
  }

  // ---- binA: bucket-bin a 4096-edge tile ----
  int* cnt = (int*)sm;                       // 196 (pad 1024)
  int* scn = (int*)(sm + 1024);
  int* gbase = (int*)(sm + 2048);
  int* cur = (int*)(sm + 3072);
  int* tmp = (int*)(sm + 4096);              // 256
  uint2* stSE = (uint2*)(sm + 5120);         // 4096*8 = 32768
  unsigned short* stD = (unsigned short*)(sm + 37888);  // 8192
  const int e0 = (blockIdx.x - NB_PREP) * TILE;

  for (int b = t; b < NB; b += 256) cnt[b] = 0;
  __syncthreads();

  unsigned int sd[16];
  float wv[16];
#pragma unroll
  for (int u = 0; u < 16; ++u) {
    int e = e0 + t + 256 * u;
    if (e < NE) {
      unsigned int s = (unsigned int)esrc[e];
      unsigned int d = (unsigned int)edst[e];
      sd[u] = s | (d << 16);
      wv[u] = ew[e];
      atomicAdd(&cnt[d >> 8], 1);
    } else {
      sd[u] = 0xFFFFFFFFu;
    }
  }
  __syncthreads();

  int v = (t < NB) ? cnt[t] : 0;
  tmp[t] = v;
  __syncthreads();
  for (int off = 1; off < 256; off <<= 1) {
    int a = (t >= off) ? tmp[t - off] : 0;
    __syncthreads();
    tmp[t] += a;
    __syncthreads();
  }
  if (t < NB) {
    scn[t] = tmp[t] - v;
    cur[t] = tmp[t] - v;
    gbase[t] = atomicAdd(&bktCnt[t], v);
  }
  __syncthreads();

#pragma unroll
  for (int u = 0; u < 16; ++u) {
    if (sd[u] != 0xFFFFFFFFu) {
      unsigned int d = sd[u] >> 16;
      int p = atomicAdd(&cur[d >> 8], 1);
      stSE[p] = make_uint2(sd[u] & 0xFFFFu, __float_as_uint(wv[u]));
      stD[p] = (unsigned short)d;
    }
  }
  __syncthreads();

  int tot = NE - e0;
  if (tot > TILE) tot = TILE;
  for (int k = t; k < tot; k += 256) {
    int d = stD[k];
    int b = d >> 8;
    int idx = gbase[b] + (k - scn[b]);
    bSrcEw[(size_t)b * BCAP + idx] = stSE[k];
    bDst[(size_t)b * BCAP + idx] = (unsigned short)d;
  }
}

// ====== k_fuse2: fillB (blocks 0..195, inline bucket-prefix) || gemm1 (blocks 196..) ======
__global__ __launch_bounds__(256) void k_fuse2(const int* __restrict__ bktCnt,
                                               const uint2* __restrict__ bSrcEw,
                                               const unsigned short* __restrict__ bDst,
                                               const float* __restrict__ ew,
                                               int* __restrict__ rs,
                                               uint2* __restrict__ edge,
                                               const float* __restrict__ x,
                                               const unsigned short* __restrict__ W1b,
                                               const float* __restrict__ attl,
                                               const float* __restrict__ attr,
                                               unsigned int* __restrict__ h1f32,
                                               float* __restrict__ al,
                                               float* __restrict__ ar) {
  __shared__ __align__(16) char sm[27136];
  const int t = threadIdx.x;

  if (blockIdx.x < NB) {
    // ---------------- fillB path ----------------
    int* cnt = (int*)sm;               // 256
    int* cur = (int*)(sm + 1024);      // 256
    int* tmp = (int*)(sm + 2048);      // 256
    int* bpre = (int*)(sm + 3072);     // 256
    int* sGb = (int*)(sm + 4096);
    const int b = blockIdx.x;
    const int n0 = b * 256;
    const int nNodes = (n0 + 256 <= NN) ? 256 : (NN - n0);

    // global bucket prefix, computed per block
    int bc = (t < NB) ? bktCnt[t] : 0;
    int nInB = 0;
    if (t < NB) nInB = (t == NB - 1) ? (NN - (NB - 1) * 256) : 256;
    int pv = bc + nInB;
    bpre[t] = pv;
    __syncthreads();
    for (int off = 1; off < 256; off <<= 1) {
      int a = (t >= off) ? bpre[t - off] : 0;
      __syncthreads();
      bpre[t] += a;
      __syncthreads();
    }
    if (t == b) *sGb = bpre[t] - pv;  // exclusive prefix at b
    if (t == 0 && b == 0) rs[NN] = NT;
    __syncthreads();
    const int gb = *sGb;
    const int cE = bktCnt[b];

    cnt[t] = 0;
    __syncthreads();
    for (int k = t; k < cE; k += 256) atomicAdd(&cnt[bDst[(size_t)b * BCAP + k] & 255], 1);
    __syncthreads();

    int v = (t < nNodes) ? cnt[t] + 1 : 0;  // +1 self loop
    tmp[t] = v;
    __syncthreads();
    for (int off = 1; off < 256; off <<= 1) {
      int a = (t >= off) ? tmp[t - off] : 0;
      __syncthreads();
      tmp[t] += a;
      __syncthreads();
    }
    int off_ = tmp[t] - v;  // exclusive
    if (t < nNodes) {
      rs[n0 + t] = gb + off_;
      cur[t] = off_ + 1;  // slot 0 = self loop
      edge[(size_t)gb + off_] = make_uint2((unsigned int)(n0 + t), __float_as_uint(ew[NE + n0 + t]));
    }
    __syncthreads();

    for (int k = t; k < cE; k += 256) {
      uint2 se = bSrcEw[(size_t)b * BCAP + k];
      int d = bDst[(size_t)b * BCAP + k] & 255;
      int p = atomicAdd(&cur[d], 1);
      edge[(size_t)gb + p] = se;  // XCD-local window
    }
    return;
  }

  // ---------------- gemm1 path: BM=32, BK=64 MFMA + fp8 pack + fused alr1 ----------------
  unsigned short* As = (unsigned short*)sm;             // 32*72*2 = 4608
  unsigned short* Bs = (unsigned short*)(sm + 4608);    // 128*72*2 = 18432
  unsigned int* pk32 = (unsigned int*)(sm + 23040);     // 4096
  const int w = t >> 6, lane = t & 63;
  const int g16 = lane >> 4, r16 = lane & 15;
  const int m0 = (blockIdx.x - NB) * 32;
  const int r0 = (w & 1) * 16;
  const int c0 = (w >> 1) * 64;

  f32x4 acc[4];
#pragma unroll
  for (int b = 0; b < 4; ++b) acc[b] = (f32x4){0.f, 0.f, 0.f, 0.f};

  for (int kc = 0; kc < NF; kc += 64) {
    __syncthreads();
#pragma unroll
    for (int i = 0; i < 2; ++i) {
      int idx = t + 256 * i;
      int row = idx >> 4;
      int k4 = (idx & 15) << 2;
      int n = m0 + row;
      float4 v = make_float4(0.f, 0.f, 0.f, 0.f);
      if (n < NN) v = *(const float4*)&x[(size_t)n * NF + kc + k4];
      short4v b;
      b[0] = (short)f2bf(v.x); b[1] = (short)f2bf(v.y);
      b[2] = (short)f2bf(v.z); b[3] = (short)f2bf(v.w);
      *(short4v*)&As[row * 72 + k4] = b;
    }
#pragma unroll
    for (int i = 0; i < 4; ++i) {
      int idx = t + 256 * i;
      int col = idx >> 3;
      int k8 = (idx & 7) << 3;
      *(short8*)&Bs[col * 72 + k8] = *(const short8*)&W1b[(size_t)col * NF + kc + k8];
    }
    __syncthreads();

    short8 afr[2], bfr[4][2];
#pragma unroll
    for (int ks = 0; ks < 2; ++ks)
      afr[ks] = *(const short8*)&As[(r0 + r16) * 72 + ks * 32 + g16 * 8];
#pragma unroll
    for (int nj = 0; nj < 4; ++nj)
#pragma unroll
      for (int ks = 0; ks < 2; ++ks)
        bfr[nj][ks] = *(const short8*)&Bs[(c0 + nj * 16 + r16) * 72 + ks * 32 + g16 * 8];
#pragma unroll
    for (int nj = 0; nj < 4; ++nj)
#pragma unroll
      for (int ks = 0; ks < 2; ++ks)
        acc[nj] = __builtin_amdgcn_mfma_f32_16x16x32_bf16(afr[ks], bfr[nj][ks], acc[nj], 0, 0, 0);
  }

  unsigned char* pkb = (unsigned char*)pk32;
  __syncthreads();
#pragma unroll
  for (int nj = 0; nj < 4; ++nj)
#pragma unroll
    for (int r = 0; r < 4; ++r)
      pkb[(r0 + g16 * 4 + r) * 128 + c0 + nj * 16 + r16] = f2fp8(acc[nj][r]);
  __syncthreads();

  {
    int row = t >> 3, q = t & 7;
    int n = m0 + row;
    if (n < NN) ((uint4*)h1f32)[(size_t)n * 8 + q] = ((const uint4*)pk32)[row * 8 + q];
  }
  {
    int row = t >> 3, h = t & 7;
    int n = m0 + row;
    if (n < NN) {
      float a = 0.f, b = 0.f;
#pragma unroll
      for (int c = 0; c < 4; ++c) {
        unsigned int u = pk32[row * 32 + h * 4 + c];
        f32x2 lo = __builtin_amdgcn_cvt_pk_f32_fp8((int)u, false);
        f32x2 hi = __builtin_amdgcn_cvt_pk_f32_fp8((int)u, true);
        int f0 = h * 16 + 4 * c;
        a = fmaf(lo[0], attl[f0], a);
        a = fmaf(lo[1], attl[f0 + 1], a);
        a = fmaf(hi[0], attl[f0 + 2], a);
        a = fmaf(hi[1], attl[f0 + 3], a);
        b = fmaf(lo[0], attr[f0], b);
        b = fmaf(lo[1], attr[f0 + 1], b);
        b = fmaf(hi[0], attr[f0 + 2], b);
        b = fmaf(hi[1], attr[f0 + 3], b);
      }
      al[n * 8 + h] = a;
      ar[n * 8 + h] = b;
    }
  }
}

// ---- layer-1 aggregation: 2 nodes/wave, 12-deep batch, plain exp, fp8 gather ----
__global__ __launch_bounds__(256) void k_agg1(const int* __restrict__ rs,
                                              const uint2* __restrict__ edge,
                                              const unsigned int* __restrict__ h1f32,
                                              const float* __restrict__ al,
                                              const float* __restrict__ ar,
                                              const float* __restrict__ b1,
                                              uint2* __restrict__ h1eb) {
  const int hl = threadIdx.x & 31;
  const int i = blockIdx.x * 8 + (threadIdx.x >> 5);
  if (i >= NN) return;
  const int base = rs[i], end = rs[i + 1];
  const int head = hl >> 2;
  const float arh = ar[i * 8 + head];
  float s0 = 0.f, s1 = 0.f;
  float a0 = 0.f, a1 = 0.f, a2 = 0.f, a3 = 0.f;
  float c0 = 0.f, c1 = 0.f, c2 = 0.f, c3 = 0.f;

  int e = base;
  for (; e + 12 <= end; e += 12) {
    uint2 ce[12];
    float lgs[12];
    unsigned int hvs[12];
#pragma unroll
    for (int u = 0; u < 12; ++u) ce[u] = edge[e + u];
#pragma unroll
    for (int u = 0; u < 12; ++u) lgs[u] = al[(int)ce[u].x * 8 + head];
#pragma unroll
    for (int u = 0; u < 12; ++u) hvs[u] = h1f32[(size_t)ce[u].x * 32 + hl];
#pragma unroll
    for (int u = 0; u < 12; ++u) {
      float q = __expf(lrelu(lgs[u] + arh));
      float pw = q * __uint_as_float(ce[u].y);
      f32x2 lo = __builtin_amdgcn_cvt_pk_f32_fp8((int)hvs[u], false);
      f32x2 hi = __builtin_amdgcn_cvt_pk_f32_fp8((int)hvs[u], true);
      if (u & 1) {
        s1 += q;
        c0 = fmaf(pw, lo[0], c0);
        c1 = fmaf(pw, lo[1], c1);
        c2 = fmaf(pw, hi[0], c2);
        c3 = fmaf(pw, hi[1], c3);
      } else {
        s0 += q;
        a0 = fmaf(pw, lo[0], a0);
        a1 = fmaf(pw, lo[1], a1);
        a2 = fmaf(pw, hi[0], a2);
        a3 = fmaf(pw, hi[1], a3);
      }
    }
  }
  for (; e + 4 <= end; e += 4) {
    uint2 ce[4];
    float lgs[4];
    unsigned int hvs[4];
#pragma unroll
    for (int u = 0; u < 4; ++u) ce[u] = edge[e + u];
#pragma unroll
    for (int u = 0; u < 4; ++u) lgs[u] = al[(int)ce[u].x * 8 + head];
#pragma unroll
    for (int u = 0; u < 4; ++u) hvs[u] = h1f32[(size_t)ce[u].x * 32 + hl];
#pragma unroll
    for (int u = 0; u < 4; ++u) {
      float q = __expf(lrelu(lgs[u] + arh));
      float pw = q * __uint_as_float(ce[u].y);
      f32x2 lo = __builtin_amdgcn_cvt_pk_f32_fp8((int)hvs[u], false);
      f32x2 hi = __builtin_amdgcn_cvt_pk_f32_fp8((int)hvs[u], true);
      if (u & 1) {
        s1 += q;
        c0 = fmaf(pw, lo[0], c0);
        c1 = fmaf(pw, lo[1], c1);
        c2 = fmaf(pw, hi[0], c2);
        c3 = fmaf(pw, hi[1], c3);
      } else {
        s0 += q;
        a0 = fmaf(pw, lo[0], a0);
        a1 = fmaf(pw, lo[1], a1);
        a2 = fmaf(pw, hi[0], a2);
        a3 = fmaf(pw, hi[1], a3);
      }
    }
  }
  for (; e < end; ++e) {
    uint2 ce = edge[e];
    int j = (int)ce.x;
    float q = __expf(lrelu(al[j * 8 + head] + arh));
    unsigned int hv = h1f32[(size_t)j * 32 + hl];
    float pw = q * __uint_as_float(ce.y);
    f32x2 lo = __builtin_amdgcn_cvt_pk_f32_fp8((int)hv, false);
    f32x2 hi = __builtin_amdgcn_cvt_pk_f32_fp8((int)hv, true);
    s0 += q;
    a0 = fmaf(pw, lo[0], a0);
    a1 = fmaf(pw, lo[1], a1);
    a2 = fmaf(pw, hi[0], a2);
    a3 = fmaf(pw, hi[1], a3);
  }
  float inv = 1.f / (s0 + s1);
  float4 bias = *(const float4*)&b1[4 * hl];
  float o0 = elu(fmaf(a0 + c0, inv, bias.x));
  float o1 = elu(fmaf(a1 + c1, inv, bias.y));
  float o2 = elu(fmaf(a2 + c2, inv, bias.z));
  float o3 = elu(fmaf(a3 + c3, inv, bias.w));
  uint2 pk;
  pk.x = (unsigned int)f2bf(o0) | ((unsigned int)f2bf(o1) << 16);
  pk.y = (unsigned int)f2bf(o2) | ((unsigned int)f2bf(o3) << 16);
  h1eb[(size_t)i * 32 + hl] = pk;
}

// ---- GEMM2 (MFMA bf16, one K-shot): hp2f[N][40] = fp8(h1e @ W2^T); fused alr2 ----
__global__ __launch_bounds__(256) void k_gemm2(const uint4* __restrict__ h1eb4,
                                               const unsigned short* __restrict__ W2b,
                                               const float* __restrict__ attl,
                                               const float* __restrict__ attr,
                                               unsigned int* __restrict__ hp2f32,
                                               float* __restrict__ al,
                                               float* __restrict__ ar) {
  __shared__ unsigned short As[64 * 136];
  __shared__ unsigned short Bs[48 * 136];
  __shared__ unsigned int pkd[64 * 10];
  const int t = threadIdx.x;
  const int w = t >> 6, lane = t & 63;
  const int g16 = lane >> 4, r16 = lane & 15;
  const int n0 = blockIdx.x * 64;

#pragma unroll
  for (int i = 0; i < 4; ++i) {
    int idx = t + 256 * i;
    int row = idx >> 4, q = idx & 15;
    int n = n0 + row;
    uint4 v = make_uint4(0u, 0u, 0u, 0u);
    if (n < NN) v = h1eb4[(size_t)n * 16 + q];
    *(uint4*)&As[row * 136 + q * 8] = v;
  }
#pragma unroll
  for (int i = 0; i < 3; ++i) {
    int idx = t + 256 * i;
    int col = idx >> 4, q = idx & 15;
    *(uint4*)&Bs[col * 136 + q * 8] = ((const uint4*)W2b)[col * 16 + q];
  }
  __syncthreads();

  f32x4 acc[3];
#pragma unroll
  for (int b = 0; b < 3; ++b) acc[b] = (f32x4){0.f, 0.f, 0.f, 0.f};
  short8 afr[4];
#pragma unroll
  for (int kc = 0; kc < 4; ++kc)
    afr[kc] = *(const short8*)&As[(w * 16 + r16) * 136 + kc * 32 + g16 * 8];
#pragma unroll
  for (int nt = 0; nt < 3; ++nt) {
#pragma unroll
    for (int kc = 0; kc < 4; ++kc) {
      short8 bfr = *(const short8*)&Bs[(nt * 16 + r16) * 136 + kc * 32 + g16 * 8];
      acc[nt] = __builtin_amdgcn_mfma_f32_16x16x32_bf16(afr[kc], bfr, acc[nt], 0, 0, 0);
    }
  }

  unsigned char* pkb = (unsigned char*)pkd;
  __syncthreads();
#pragma unroll
  for (int nt = 0; nt < 3; ++nt) {
    int col = nt * 16 + r16;
    if (col < 40) {
#pragma unroll
      for (int r = 0; r < 4; ++r)
        pkb[(w * 16 + g16 * 4 + r) * 40 + col] = f2fp8(acc[nt][r]);
    }
  }
  __syncthreads();

  for (int idx = t; idx < 640; idx += 256) {
    int row = idx / 10, q = idx - row * 10;
    int n = n0 + row;
    if (n < NN) hp2f32[(size_t)n * 10 + q] = pkd[row * 10 + q];
  }
  if (t < 64) {
    int n = n0 + t;
    if (n < NN) {
      float a = 0.f, b = 0.f;
#pragma unroll
      for (int c = 0; c < 10; ++c) {
        unsigned int u = pkd[t * 10 + c];
        f32x2 lo = __builtin_amdgcn_cvt_pk_f32_fp8((int)u, false);
        f32x2 hi = __builtin_amdgcn_cvt_pk_f32_fp8((int)u, true);
        a = fmaf(lo[0], attl[4 * c], a);
        a = fmaf(lo[1], attl[4 * c + 1], a);
        a = fmaf(hi[0], attl[4 * c + 2], a);
        a = fmaf(hi[1], attl[4 * c + 3], a);
        b = fmaf(lo[0], attr[4 * c], b);
        b = fmaf(lo[1], attr[4 * c + 1], b);
        b = fmaf(hi[0], attr[4 * c + 2], b);
        b = fmaf(hi[1], attr[4 * c + 3], b);
      }
      al[n] = a;
      ar[n] = b;
    }
  }
}

// ---- layer-2 attention prepass: 2 nodes/wave; edge.y <- q*ew, sinv[i] = 1/sum(q) ----
__global__ __launch_bounds__(256) void k_qw2(const int* __restrict__ rs,
                                             uint2* __restrict__ edge,
                                             const float* __restrict__ al2,
                                             const float* __restrict__ ar2,
                                             float* __restrict__ sinv) {
  const int l = threadIdx.x & 31;
  const int i = blockIdx.x * 8 + (threadIdx.x >> 5);
  if (i >= NN) return;
  const int base = rs[i], end = rs[i + 1];
  const float ari = ar2[i];
  float s = 0.f;
  for (int e = base + l; e < end; e += 32) {
    uint2 ce = edge[e];
    float q = __expf(lrelu(al2[(int)ce.x] + ari));
    s += q;
    ((float*)&edge[e])[1] = q * __uint_as_float(ce.y);
  }
#pragma unroll
  for (int off = 1; off < 32; off <<= 1) s += __shfl_xor(s, off, 32);
  if (l == 0) sinv[i] = 1.f / s;
}

// ---- layer-2 aggregation + bias + log_softmax: 2 nodes/wave, 16-deep batch ----
__global__ __launch_bounds__(256) void k_agg2(const int* __restrict__ rs,
                                              const uint2* __restrict__ edge,
                                              const unsigned short* __restrict__ hp2f16,
                                              const float* __restrict__ sinv,
                                              const float* __restrict__ b2,
                                              float* __restrict__ out) {
  const int hl = threadIdx.x & 31;
  const int i = blockIdx.x * 8 + (threadIdx.x >> 5);
  if (i >= NN) return;
  const int base = rs[i], end = rs[i + 1];
  float a0 = 0.f, a1 = 0.f, c0 = 0.f, c1 = 0.f;

  int e = base;
  for (; e + 16 <= end; e += 16) {
    uint2 ce[16];
#pragma unroll
    for (int u = 0; u < 16; ++u) ce[u] = edge[e + u];
    unsigned int hv[16];
#pragma unroll
    for (int u = 0; u < 16; ++u)
      hv[u] = (hl < 20) ? (unsigned int)hp2f16[(size_t)ce[u].x * 20 + hl] : 0u;
#pragma unroll
    for (int u = 0; u < 16; ++u) {
      float p = __uint_as_float(ce[u].y);
      f32x2 v = __builtin_amdgcn_cvt_pk_f32_fp8((int)hv[u], false);
      if (u & 1) {
        c0 = fmaf(p, v[0], c0);
        c1 = fmaf(p, v[1], c1);
      } else {
        a0 = fmaf(p, v[0], a0);
        a1 = fmaf(p, v[1], a1);
      }
    }
  }
  for (; e + 4 <= end; e += 4) {
    uint2 ce[4];
#pragma unroll
    for (int u = 0; u < 4; ++u) ce[u] = edge[e + u];
    unsigned int hv[4];
#pragma unroll
    for (int u = 0; u < 4; ++u)
      hv[u] = (hl < 20) ? (unsigned int)hp2f16[(size_t)ce[u].x * 20 + hl] : 0u;
#pragma unroll
    for (int u = 0; u < 4; ++u) {
      float p = __uint_as_float(ce[u].y);
      f32x2 v = __builtin_amdgcn_cvt_pk_f32_fp8((int)hv[u], false);
      if (u & 1) {
        c0 = fmaf(p, v[0], c0);
        c1 = fmaf(p, v[1], c1);
      } else {
        a0 = fmaf(p, v[0], a0);
        a1 = fmaf(p, v[1], a1);
      }
    }
  }
  for (; e < end; ++e) {
    uint2 ce = edge[e];
    unsigned int hv = (hl < 20) ? (unsigned int)hp2f16[(size_t)ce.x * 20 + hl] : 0u;
    float p = __uint_as_float(ce.y);
    f32x2 v = __builtin_amdgcn_cvt_pk_f32_fp8((int)hv, false);
    a0 = fmaf(p, v[0], a0);
    a1 = fmaf(p, v[1], a1);
  }
  a0 += c0;
  a1 += c1;
  float inv = sinv[i];
  float v0 = -1e30f, v1 = -1e30f;
  if (hl < 20) {
    v0 = fmaf(a0, inv, b2[2 * hl]);
    v1 = fmaf(a1, inv, b2[2 * hl + 1]);
  }
  float mx = fmaxf(v0, v1);
#pragma unroll
  for (int off = 1; off < 32; off <<= 1) mx = fmaxf(mx, __shfl_xor(mx, off, 32));
  float se = (hl < 20) ? __expf(v0 - mx) + __expf(v1 - mx) : 0.f;
#pragma unroll
  for (int off = 1; off < 32; off <<= 1) se += __shfl_xor(se, off, 32);
  if (hl < 20) {
    float ls = mx + __logf(se);
    ((float2*)(out + (size_t)i * 40))[hl] = make_float2(v0 - ls, v1 - ls);
  }
}

extern "C" void kernel_launch(void* const* d_in, const int* in_sizes, int n_in,
                              void* d_out, int out_size, void* d_ws, size_t ws_size,
                              hipStream_t stream) {
  const float* x     = (const float*)d_in[0];
  const int*   esrc  = (const int*)d_in[1];
  const int*   edst  = (const int*)d_in[2];
  const float* ew    = (const float*)d_in[3];
  const float* W1    = (const float*)d_in[4];
  const float* attl1 = (const float*)d_in[5];
  const float* attr1 = (const float*)d_in[6];
  const float* b1    = (const float*)d_in[7];
  const float* W2    = (const float*)d_in[8];
  const float* attl2 = (const float*)d_in[9];
  const float* attr2 = (const float*)d_in[10];
  const float* b2    = (const float*)d_in[11];
  float* out = (float*)d_out;

  char* w = (char*)d_ws;
  auto take = [&](size_t bytes) {
    char* p = w;
    w += (bytes + 255) & ~(size_t)255;
    return p;
  };
  unsigned int* h1f  = (unsigned int*)take((size_t)NN * F1);       // fp8 table, 6.4 MB
  unsigned int* h1eb = (unsigned int*)take((size_t)NN * 64 * 4);   // bf16, 12.8 MB
  float* al1 = (float*)take((size_t)NN * NH * 4);
  float* ar1 = (float*)take((size_t)NN * NH * 4);
  unsigned int* hp2f = (unsigned int*)take((size_t)NN * 40);       // fp8 table, 2 MB
  float* al2 = (float*)take((size_t)NN * 4);
  float* ar2 = (float*)take((size_t)NN * 4);
  float* sinv = (float*)take((size_t)NN * 4);
  int*   rs  = (int*)take((size_t)(NN + 1) * 4);
  uint2* edge = (uint2*)take((size_t)NT * 8);
  unsigned short* W1b = (unsigned short*)take((size_t)F1 * NF * 2); // 128 KB bf16 W1
  unsigned short* W2b = (unsigned short*)take((size_t)48 * 128 * 2); // 12 KB bf16 W2 (pad 48)
  int* bktCnt = (int*)take(NB * 4);
  // DEDICATED staging (no aliasing! fillB runs concurrently with gemm1 which writes h1f/al1)
  uint2* bSrcEw = (uint2*)take((size_t)NB * BCAP * 8);              // 16.06 MB
  unsigned short* bDst = (unsigned short*)take((size_t)NB * BCAP * 2);  // 4.01 MB

  hipMemsetAsync(bktCnt, 0, NB * 4, stream);
  // wprep || binA
  k_prep<<<NB_PREP + NB_BINA, 256, 0, stream>>>(W1, W2, W1b, W2b,
                                                esrc, edst, ew, bktCnt, bSrcEw, bDst);
  // fillB (with inline bucket scan) || gemm1(+alr1)
  k_fuse2<<<NB + NB_G1, 256, 0, stream>>>(bktCnt, bSrcEw, bDst, ew, rs, edge,
                                          x, W1b, attl1, attr1, h1f, al1, ar1);
  // layer-1 aggregation
  k_agg1<<<(NN + 7) / 8, 256, 0, stream>>>(rs, edge, h1f, al1, ar1, b1, (uint2*)h1eb);
  // layer 2
  k_gemm2<<<(NN + 63) / 64, 256, 0, stream>>>((const uint4*)h1eb, W2b, attl2, attr2,
                                              hp2f, al2, ar2);
  k_qw2<<<(NN + 7) / 8, 256, 0, stream>>>(rs, edge, al2, ar2, sinv);
  k_agg2<<<(NN + 7) / 8, 256, 0, stream>>>(rs, edge, (const unsigned short*)hp2f, sinv, b2, out);
}